// Round 11
// baseline (117.863 us; speedup 1.0000x reference)
//
#include <hip/hip_runtime.h>

typedef unsigned short u16;
typedef __bf16 bf16_t;
typedef bf16_t bf16x8 __attribute__((ext_vector_type(8)));
typedef float f32x4 __attribute__((ext_vector_type(4)));
typedef u16 u16x8 __attribute__((ext_vector_type(8)));
typedef u16 u16x4 __attribute__((ext_vector_type(4)));

__device__ __forceinline__ u16 f2bf(float f) {
  unsigned u = __float_as_uint(f);
  u += 0x7fffu + ((u >> 16) & 1u);
  return (u16)(u >> 16);
}

__device__ __forceinline__ float bf2f(u16 u) {
  return __uint_as_float((unsigned)u << 16);
}

__device__ __forceinline__ unsigned cvtpk(float lo, float hi) {
  unsigned r;
  asm("v_cvt_pk_bf16_f32 %0, %1, %2" : "=v"(r) : "v"(lo), "v"(hi));
  return r;
}

__device__ __forceinline__ f32x4 mfma16(bf16x8 a, bf16x8 b, f32x4 c) {
  return __builtin_amdgcn_mfma_f32_16x16x32_bf16(a, b, c, 0, 0, 0);
}

__device__ __forceinline__ void gl2lds16(const u16* g, u16* l) {
  __builtin_amdgcn_global_load_lds(
      (__attribute__((address_space(1))) void*)(u16*)g,
      (__attribute__((address_space(3))) void*)l, 16, 0, 0);
}

__device__ __forceinline__ void cast8(const float* __restrict__ in,
                                      u16* __restrict__ out, int i) {
  float4 a = *(const float4*)&in[i];
  float4 b = *(const float4*)&in[i + 4];
  uint4 o;
  o.x = cvtpk(a.x, a.y);
  o.y = cvtpk(a.z, a.w);
  o.z = cvtpk(b.x, b.y);
  o.w = cvtpk(b.z, b.w);
  *(uint4*)&out[i] = o;
}

// ---------------- megacast: all f32->bf16 casts + trig table, one launch ----
__global__ __launch_bounds__(256) void megacast(
    const float* __restrict__ x, const float* __restrict__ Wq,
    const float* __restrict__ Wk, const float* __restrict__ Wv,
    const float* __restrict__ Wp, u16* __restrict__ xb,
    u16* __restrict__ wallb, u16* __restrict__ wpb,
    float2* __restrict__ tbl) {
  const int blk = blockIdx.x;
  const int tid = threadIdx.x;
  if (blk < 2048) {
    cast8(x, xb, (blk * 256 + tid) * 8);
  } else if (blk < 2560) {
    cast8(Wq, wallb, ((blk - 2048) * 256 + tid) * 8);
  } else if (blk < 2688) {
    cast8(Wk, wallb + 1048576, ((blk - 2560) * 256 + tid) * 8);
  } else if (blk < 2816) {
    cast8(Wv, wallb + 1310720, ((blk - 2688) * 256 + tid) * 8);
  } else if (blk < 3328) {
    cast8(Wp, wpb, ((blk - 2816) * 256 + tid) * 8);
  } else {
    const int idx = (blk - 3328) * 256 + tid;  // < 65536
    const int s = idx >> 5, i = idx & 31;
    float inv = exp2f(-(float)i * (13.287712379549449f / 32.0f));
    float fr = (float)s * inv;
    float sn, cs;
    sincosf(fr, &sn, &cs);
    tbl[idx] = make_float2(cs, sn);
  }
}

// ---------------- GEMM: C[M][N] = A[M][K] * B[N][K]^T, tiled BMxBN ----------
template <int BM, int BN, bool O16>
__global__ __launch_bounds__(256) void gemm_bt(const u16* __restrict__ A,
                                               const u16* __restrict__ B,
                                               void* __restrict__ Cv,
                                               int M, int N, int K) {
  constexpr int FM = BM / 32;
  constexpr int FN = BN / 32;
  constexpr int NL = (BM + BN) / 32;
  __shared__ __align__(16) u16 As[2][BM][64];
  __shared__ __align__(16) u16 Bs[2][BN][64];
  const int tid = threadIdx.x;
  const int lane = tid & 63;
  const int lg = lane >> 4, li = lane & 15;
  const int wave = tid >> 6;
  const int wr = (wave >> 1) * (BM / 2), wc = (wave & 1) * (BN / 2);
  const int m0 = blockIdx.y * BM, n0 = blockIdx.x * BN;

  const int s_r = tid >> 3;
  const int s_c = (tid & 7) ^ ((tid >> 3) & 7);
  const int rdsw = li & 7;

  auto GSTAGE = [&](int buf, int k0) {
    const u16* ga = &A[(size_t)(m0 + s_r) * K + k0 + s_c * 8];
#pragma unroll
    for (int i = 0; i < BM / 32; i++)
      gl2lds16(ga + (size_t)(i * 32) * K, &As[buf][i * 32][0] + (size_t)tid * 8);
    const u16* gb = &B[(size_t)(n0 + s_r) * K + k0 + s_c * 8];
#pragma unroll
    for (int i = 0; i < BN / 32; i++)
      gl2lds16(gb + (size_t)(i * 32) * K, &Bs[buf][i * 32][0] + (size_t)tid * 8);
  };

  const f32x4 fz = {0.f, 0.f, 0.f, 0.f};
  f32x4 acc[FM][FN];
#pragma unroll
  for (int i = 0; i < FM; i++)
#pragma unroll
    for (int j = 0; j < FN; j++) acc[i][j] = fz;

  GSTAGE(0, 0);
  int buf = 0;
  const int nk = K >> 6;
  for (int t = 0; t < nk; ++t) {
    if (t + 1 < nk) {
      GSTAGE(buf ^ 1, (t + 1) * 64);
      if constexpr (NL == 6)
        asm volatile("s_waitcnt vmcnt(6)" ::: "memory");
      else if constexpr (NL == 7)
        asm volatile("s_waitcnt vmcnt(7)" ::: "memory");
      else
        asm volatile("s_waitcnt vmcnt(8)" ::: "memory");
    } else {
      asm volatile("s_waitcnt vmcnt(0)" ::: "memory");
    }
    __builtin_amdgcn_s_barrier();
#pragma unroll
    for (int kk = 0; kk < 2; kk++) {
      bf16x8 af[FM], bfr[FN];
#pragma unroll
      for (int i = 0; i < FM; i++)
        af[i] = *(const bf16x8*)&As[buf][wr + i * 16 + li]
                                   [((kk * 4 + lg) ^ rdsw) * 8];
#pragma unroll
      for (int j = 0; j < FN; j++)
        bfr[j] = *(const bf16x8*)&Bs[buf][wc + j * 16 + li]
                                    [((kk * 4 + lg) ^ rdsw) * 8];
      __builtin_amdgcn_s_setprio(1);
#pragma unroll
      for (int i = 0; i < FM; i++)
#pragma unroll
        for (int j = 0; j < FN; j++) acc[i][j] = mfma16(af[i], bfr[j], acc[i][j]);
      __builtin_amdgcn_s_setprio(0);
    }
    __builtin_amdgcn_s_barrier();
    buf ^= 1;
  }
#pragma unroll
  for (int i = 0; i < FM; i++)
#pragma unroll
    for (int j = 0; j < FN; j++)
#pragma unroll
      for (int r = 0; r < 4; r++) {
        const size_t idx =
            (size_t)(m0 + wr + i * 16 + lg * 4 + r) * N + n0 + wc + j * 16 + li;
        if constexpr (O16)
          ((u16*)Cv)[idx] = f2bf(acc[i][j][r]);
        else
          ((float*)Cv)[idx] = acc[i][j][r];
      }
}

// ---------------- fused RMSNorm + RoPE for 20 heads (16 q + 4 k) ------------
__global__ __launch_bounds__(256) void rmsropeqk(const u16* __restrict__ in,
                                                 const float* __restrict__ qg,
                                                 u16* __restrict__ qhb,
                                                 u16* __restrict__ khb, int S,
                                                 const float2* __restrict__ tbl) {
  const int w = threadIdx.x >> 6;
  const int t = threadIdx.x & 63;
  const int row = blockIdx.x * 4 + w;
  const int h = blockIdx.y;  // 0..19
  const bool isq = h < 16;
  const int col = isq ? h * 64 : 1024 + (h - 16) * 64;
  const float v = bf2f(in[(size_t)row * 1536 + col + t]);
  float ss = v * v;
#pragma unroll
  for (int m = 1; m < 64; m <<= 1) ss += __shfl_xor(ss, m);
  const float vn = v * rsqrtf(ss * (1.0f / 64.0f) + 1.1920929e-07f);
  const float partner = __shfl_xor(vn, 32);
  const int b = row / S;
  const int s = row - b * S;
  const float2 cs2 = tbl[s * 32 + (t & 31)];
  float o = (t < 32) ? (vn * cs2.x + partner * cs2.y)
                     : (vn * cs2.x - partner * cs2.y);
  if (isq) {
    o *= 0.18033688011112042f * qg[h];
    qhb[((size_t)(b * 16 + h) * S + s) * 64 + t] = f2bf(o);
  } else {
    khb[((size_t)(b * 4 + (h - 16)) * S + s) * 64 + t] = f2bf(o);
  }
}

// ---------------- V transpose via LDS ----------------
__global__ __launch_bounds__(256) void vcast2(const u16* __restrict__ qf,
                                              u16* __restrict__ vt, int S) {
  const int blk = blockIdx.x;
  const int sc = blk & 7;
  const int kv = (blk >> 3) & 3;
  const int b = blk >> 5;
  __shared__ u16 T[256][66];
  const int tid = threadIdx.x;
  const int dcol = tid & 63;
  const int w = tid >> 6;
  const u16* src =
      qf + (size_t)(b * S + sc * 256) * 1536 + 1280 + kv * 64 + dcol;
#pragma unroll 4
  for (int i = 0; i < 64; ++i) {
    const int sl = i * 4 + w;
    T[sl][dcol] = src[(size_t)sl * 1536];
  }
  __syncthreads();
  u16* dst = vt + (size_t)((b * 4 + kv) * 64) * S + sc * 256;
  const int l = tid & 63;
#pragma unroll 4
  for (int i = 0; i < 16; ++i) {
    const int drow = i * 4 + w;
    u16x4 v4;
    v4[0] = T[l * 4 + 0][drow];
    v4[1] = T[l * 4 + 1][drow];
    v4[2] = T[l * 4 + 2][drow];
    v4[3] = T[l * 4 + 3][drow];
    *(u16x4*)(dst + (size_t)drow * S + l * 4) = v4;
  }
}

// ---------------- flash attention v9: uniform KV-split blocks ---------------
// Max-free softmax (per-head constant bound) => partial (o,lsum) over disjoint
// KV ranges combine by addition. grid 1024: idx = bh*32 + dd*2 + half.
// half 0: tile 31-dd, kv 0..15 (16 iters) -> scr0 partial.
// half 1: tile 31-dd, kv 16..31-dd -> scr1 partial; then tile dd full -> y.
__global__ __launch_bounds__(256) void attn9(const u16* __restrict__ qh,
                                             const u16* __restrict__ kh,
                                             const u16* __restrict__ vt,
                                             const float* __restrict__ qg,
                                             u16* __restrict__ y,
                                             float* __restrict__ scr0,
                                             float* __restrict__ scr1, int S) {
  const int idx = blockIdx.x;
  const int half = idx & 1;
  const int dd = (idx >> 1) & 15;
  const int bh = idx >> 5;
  const int h = bh & 15, b = bh >> 4;
  const int kvh = h >> 2;
  const int p = bh * 16 + dd;  // pair id for scratch
  const int tid = threadIdx.x;
  const int wave = tid >> 6;
  const int lane = tid & 63;
  const int lg = lane >> 4, li = lane & 15;
  const float mrow = 11.541560327111707f * fabsf(qg[h]);

  const u16* kp = kh + (size_t)(b * 4 + kvh) * S * 64;
  const u16* vp = vt + (size_t)(b * 4 + kvh) * 64 * S;

  __shared__ __align__(16) u16 Ks[2][64][64];
  __shared__ __align__(16) u16 Vs[2][64][64];
  __shared__ __align__(16) u16 Ps[4][16][64];

  const int s_r0 = tid >> 3;
  const int s_c = (tid & 7) ^ ((tid >> 3) & 7);
  char* psrow = (char*)&Ps[wave][li][0];
  const int swz = li & 7;
  const int rdsw = li & 7;
  const f32x4 minit = {-mrow, -mrow, -mrow, -mrow};
  const f32x4 fz = {0.f, 0.f, 0.f, 0.f};
  const u16x8 ones_u = {0x3F80, 0x3F80, 0x3F80, 0x3F80,
                        0x3F80, 0x3F80, 0x3F80, 0x3F80};
  const bf16x8 onesb = *(const bf16x8*)&ones_u;

#define STAGE(buf, kb)                                                        \
  {                                                                           \
    const u16* gk = kp + (size_t)((kb) + s_r0) * 64 + s_c * 8;                \
    gl2lds16(gk, &Ks[buf][0][0] + (size_t)tid * 8);                           \
    gl2lds16(gk + (size_t)32 * 64, &Ks[buf][32][0] + (size_t)tid * 8);        \
    const u16* gv = vp + (size_t)s_r0 * S + (kb) + s_c * 8;                   \
    gl2lds16(gv, &Vs[buf][0][0] + (size_t)tid * 8);                           \
    gl2lds16(gv + (size_t)32 * S, &Vs[buf][32][0] + (size_t)tid * 8);         \
  }

  int buf = 0;

  // mode: 0 -> scr0 partial, 1 -> scr1 partial, 2 -> direct y (divide)
  auto runseg = [&](int qt, int t0, int t1, int mode, int next_t0) {
    const int q0 = qt * 64 + wave * 16;
    const int qrow = q0 + li;
    const u16* qp = qh + ((size_t)(b * 16 + h) * S + q0) * 64;
    const bf16x8 qf0 = *(const bf16x8*)&qp[li * 64 + lg * 8];
    const bf16x8 qf1 = *(const bf16x8*)&qp[li * 64 + 32 + lg * 8];
    f32x4 o[4];
#pragma unroll
    for (int j = 0; j < 4; j++) o[j] = fz;
    f32x4 lsum = fz;

    for (int tt = t0; tt < t1; ++tt) {
      if (tt + 1 < t1) {
        STAGE(buf ^ 1, (tt + 1) * 64)
        asm volatile("s_waitcnt vmcnt(4)" ::: "memory");
      } else if (next_t0 >= 0) {
        STAGE(buf ^ 1, next_t0 * 64)
        asm volatile("s_waitcnt vmcnt(4)" ::: "memory");
      } else {
        asm volatile("s_waitcnt vmcnt(0)" ::: "memory");
      }
      __builtin_amdgcn_s_barrier();
      const int kb = tt * 64;
      f32x4 s[4];
      __builtin_amdgcn_s_setprio(1);
#pragma unroll
      for (int t = 0; t < 4; t++) {
        const bf16x8 ka =
            *(const bf16x8*)&Ks[buf][t * 16 + li][((lg) ^ rdsw) * 8];
        const bf16x8 kc =
            *(const bf16x8*)&Ks[buf][t * 16 + li][((lg + 4) ^ rdsw) * 8];
        s[t] = mfma16(ka, qf0, minit);
        s[t] = mfma16(kc, qf1, s[t]);
      }
      __builtin_amdgcn_s_setprio(0);
      float pv[16];
      if (tt == qt) {  // diagonal tile: causal mask
#pragma unroll
        for (int t = 0; t < 4; t++)
#pragma unroll
          for (int r = 0; r < 4; r++) {
            const float x =
                (kb + t * 16 + lg * 4 + r > qrow) ? -1e30f : s[t][r];
            pv[t * 4 + r] = exp2f(x);
          }
      } else {
#pragma unroll
        for (int t = 0; t < 4; t++)
#pragma unroll
          for (int r = 0; r < 4; r++) pv[t * 4 + r] = exp2f(s[t][r]);
      }
#pragma unroll
      for (int t = 0; t < 4; t++) {
        uint2 w;
        w.x = cvtpk(pv[t * 4 + 0], pv[t * 4 + 1]);
        w.y = cvtpk(pv[t * 4 + 2], pv[t * 4 + 3]);
        const int c8 = (t * 4 + lg) ^ (swz << 1);
        *(uint2*)(psrow + c8 * 8) = w;
      }
      const bf16x8 pa0 = *(const bf16x8*)(psrow + ((lg + 0) ^ swz) * 16);
      const bf16x8 pa1 = *(const bf16x8*)(psrow + ((lg + 4) ^ swz) * 16);
      __builtin_amdgcn_s_setprio(1);
#pragma unroll
      for (int j = 0; j < 4; j++) {
        const bf16x8 v0 =
            *(const bf16x8*)&Vs[buf][j * 16 + li][((lg) ^ rdsw) * 8];
        const bf16x8 v1 =
            *(const bf16x8*)&Vs[buf][j * 16 + li][((lg + 4) ^ rdsw) * 8];
        o[j] = mfma16(pa0, v0, o[j]);
        o[j] = mfma16(pa1, v1, o[j]);
      }
      lsum = mfma16(pa0, onesb, lsum);
      lsum = mfma16(pa1, onesb, lsum);
      __builtin_amdgcn_s_setprio(0);
      __builtin_amdgcn_s_barrier();
      buf ^= 1;
    }

    if (mode == 2) {
#pragma unroll
      for (int j = 0; j < 4; j++)
#pragma unroll
        for (int r = 0; r < 4; r++)
          y[((size_t)(b * S + q0 + lg * 4 + r)) * 1024 + h * 64 + j * 16 + li] =
              f2bf(o[j][r] / lsum[r]);
    } else {
      float* scr = (mode == 0 ? scr0 : scr1) + (size_t)p * 4160;
#pragma unroll
      for (int j = 0; j < 4; j++)
#pragma unroll
        for (int r = 0; r < 4; r++)
          scr[(wave * 16 + lg * 4 + r) * 64 + j * 16 + li] = o[j][r];
      if (li == 0) {
#pragma unroll
        for (int r = 0; r < 4; r++)
          scr[4096 + wave * 16 + lg * 4 + r] = lsum[r];
      }
    }
  };

  if (half == 0) {
    STAGE(0, 0)
    runseg(31 - dd, 0, 16, 0, -1);
  } else {
    STAGE(0, 16 * 64)
    runseg(31 - dd, 16, 32 - dd, 1, 0);
    runseg(dd, 0, dd + 1, 2, -1);
  }
#undef STAGE
}

// ---------------- combine split-tile partials, write y ----------------
__global__ __launch_bounds__(256) void attnred(const float* __restrict__ scr0,
                                               const float* __restrict__ scr1,
                                               u16* __restrict__ y, int S) {
  const int p = blockIdx.x;        // 512
  const int bh = p >> 4, dd = p & 15;
  const int qt = 31 - dd;
  const int b = bh >> 4, h = bh & 15;
  const int tid = threadIdx.x;
  const int row = tid >> 2, cq = (tid & 3) * 16;
  const size_t base = (size_t)p * 4160;
  const float linv =
      1.0f / (scr0[base + 4096 + row] + scr1[base + 4096 + row]);
  const float* o0 = scr0 + base + row * 64 + cq;
  const float* o1 = scr1 + base + row * 64 + cq;
  u16 ov[16];
#pragma unroll
  for (int c = 0; c < 16; c += 4) {
    float4 a = *(const float4*)(o0 + c);
    float4 bb = *(const float4*)(o1 + c);
    *(unsigned*)&ov[c] = cvtpk((a.x + bb.x) * linv, (a.y + bb.y) * linv);
    *(unsigned*)&ov[c + 2] = cvtpk((a.z + bb.z) * linv, (a.w + bb.w) * linv);
  }
  u16* yp = &y[((size_t)(b * S + qt * 64 + row)) * 1024 + h * 64 + cq];
  *(uint4*)yp = *(uint4*)&ov[0];          // cols cq .. cq+7
  *(uint4*)(yp + 8) = *(uint4*)&ov[8];    // cols cq+8 .. cq+15  (was missing)
}

extern "C" void kernel_launch(void* const* d_in, const int* in_sizes, int n_in,
                              void* d_out, int out_size, void* d_ws, size_t ws_size,
                              hipStream_t stream) {
  const float* x  = (const float*)d_in[0];
  const float* Wq = (const float*)d_in[1];
  const float* Wk = (const float*)d_in[2];
  const float* Wv = (const float*)d_in[3];
  const float* Wp = (const float*)d_in[4];
  const float* qg = (const float*)d_in[5];
  float* out = (float*)d_out;

  const int S = 2048;
  char* ws = (char*)d_ws;
  u16*    xb    = (u16*)(ws + 0);          // 8 MB (dead after QKV gemm)
  u16*    wallb = (u16*)(ws + 8388608);    // 3 MB (dead after QKV gemm)
  u16*    wpb   = (u16*)(ws + 11534336);   // 2 MB (live to end)
  float2* tbl   = (float2*)(ws + 13631488);// 512 KB (dead after rmsropeqk)
  u16*    qf    = (u16*)(ws + 14155776);   // 12 MB (dead after vcast2)
  u16*    qhb   = (u16*)(ws + 26738688);   // 8 MB
  u16*    khb   = (u16*)(ws + 35127296);   // 2 MB
  u16*    vtb   = (u16*)(ws + 37224448);   // 2 MB
  u16*    yb    = (u16*)(ws + 39321600);   // 8 MB -> 47710208
  // attn scratch reuses dead regions: scr0 over xb/wallb, scr1 over qf
  float*  scr0  = (float*)(ws + 0);        // 512*4160*4 = 8.52 MB (< 11.5)
  float*  scr1  = (float*)(ws + 14155776); // 8.52 MB (< 12.58)
  if (ws_size < 47710208) return;

  megacast<<<3584, 256, 0, stream>>>(x, Wq, Wk, Wv, Wp, xb, wallb, wpb, tbl);

  gemm_bt<128, 96, true><<<dim3(16, 32), 256, 0, stream>>>(xb, wallb, qf,
                                                           4096, 1536, 1024);

  rmsropeqk<<<dim3(1024, 20), 256, 0, stream>>>(qf, qg, qhb, khb, S, tbl);
  vcast2<<<64, 256, 0, stream>>>(qf, vtb, S);

  attn9<<<1024, 256, 0, stream>>>(qhb, khb, vtb, qg, yb, scr0, scr1, S);
  attnred<<<512, 256, 0, stream>>>(scr0, scr1, yb, S);

  gemm_bt<64, 128, false><<<dim3(8, 64), 256, 0, stream>>>(yb, wpb, out,
                                                           4096, 1024, 1024);
}

// Round 12
// 116.718 us; speedup vs baseline: 1.0098x; 1.0098x over previous
//
#include <hip/hip_runtime.h>

typedef unsigned short u16;
typedef __bf16 bf16_t;
typedef bf16_t bf16x8 __attribute__((ext_vector_type(8)));
typedef float f32x4 __attribute__((ext_vector_type(4)));
typedef u16 u16x8 __attribute__((ext_vector_type(8)));
typedef u16 u16x4 __attribute__((ext_vector_type(4)));

__device__ __forceinline__ u16 f2bf(float f) {
  unsigned u = __float_as_uint(f);
  u += 0x7fffu + ((u >> 16) & 1u);
  return (u16)(u >> 16);
}

__device__ __forceinline__ float bf2f(u16 u) {
  return __uint_as_float((unsigned)u << 16);
}

__device__ __forceinline__ unsigned cvtpk(float lo, float hi) {
  unsigned r;
  asm("v_cvt_pk_bf16_f32 %0, %1, %2" : "=v"(r) : "v"(lo), "v"(hi));
  return r;
}

__device__ __forceinline__ f32x4 mfma16(bf16x8 a, bf16x8 b, f32x4 c) {
  return __builtin_amdgcn_mfma_f32_16x16x32_bf16(a, b, c, 0, 0, 0);
}

__device__ __forceinline__ void gl2lds16(const u16* g, u16* l) {
  __builtin_amdgcn_global_load_lds(
      (__attribute__((address_space(1))) void*)(u16*)g,
      (__attribute__((address_space(3))) void*)l, 16, 0, 0);
}

__device__ __forceinline__ void cast8(const float* __restrict__ in,
                                      u16* __restrict__ out, int i) {
  float4 a = *(const float4*)&in[i];
  float4 b = *(const float4*)&in[i + 4];
  uint4 o;
  o.x = cvtpk(a.x, a.y);
  o.y = cvtpk(a.z, a.w);
  o.z = cvtpk(b.x, b.y);
  o.w = cvtpk(b.z, b.w);
  *(uint4*)&out[i] = o;
}

// ---------------- megacast: all f32->bf16 casts + trig table, one launch ----
__global__ __launch_bounds__(256) void megacast(
    const float* __restrict__ x, const float* __restrict__ Wq,
    const float* __restrict__ Wk, const float* __restrict__ Wv,
    const float* __restrict__ Wp, u16* __restrict__ xb,
    u16* __restrict__ wallb, u16* __restrict__ wpb,
    float2* __restrict__ tbl) {
  const int blk = blockIdx.x;
  const int tid = threadIdx.x;
  if (blk < 2048) {
    cast8(x, xb, (blk * 256 + tid) * 8);
  } else if (blk < 2560) {
    cast8(Wq, wallb, ((blk - 2048) * 256 + tid) * 8);
  } else if (blk < 2688) {
    cast8(Wk, wallb + 1048576, ((blk - 2560) * 256 + tid) * 8);
  } else if (blk < 2816) {
    cast8(Wv, wallb + 1310720, ((blk - 2688) * 256 + tid) * 8);
  } else if (blk < 3328) {
    cast8(Wp, wpb, ((blk - 2816) * 256 + tid) * 8);
  } else {
    const int idx = (blk - 3328) * 256 + tid;  // < 65536
    const int s = idx >> 5, i = idx & 31;
    float inv = exp2f(-(float)i * (13.287712379549449f / 32.0f));
    float fr = (float)s * inv;
    float sn, cs;
    sincosf(fr, &sn, &cs);
    tbl[idx] = make_float2(cs, sn);
  }
}

// ---------------- GEMM: C[M][N] = A[M][K] * B[N][K]^T, tiled BMxBN ----------
template <int BM, int BN, bool O16>
__global__ __launch_bounds__(256) void gemm_bt(const u16* __restrict__ A,
                                               const u16* __restrict__ B,
                                               void* __restrict__ Cv,
                                               int M, int N, int K) {
  constexpr int FM = BM / 32;
  constexpr int FN = BN / 32;
  constexpr int NL = (BM + BN) / 32;
  __shared__ __align__(16) u16 As[2][BM][64];
  __shared__ __align__(16) u16 Bs[2][BN][64];
  const int tid = threadIdx.x;
  const int lane = tid & 63;
  const int lg = lane >> 4, li = lane & 15;
  const int wave = tid >> 6;
  const int wr = (wave >> 1) * (BM / 2), wc = (wave & 1) * (BN / 2);
  const int m0 = blockIdx.y * BM, n0 = blockIdx.x * BN;

  const int s_r = tid >> 3;
  const int s_c = (tid & 7) ^ ((tid >> 3) & 7);
  const int rdsw = li & 7;

  auto GSTAGE = [&](int buf, int k0) {
    const u16* ga = &A[(size_t)(m0 + s_r) * K + k0 + s_c * 8];
#pragma unroll
    for (int i = 0; i < BM / 32; i++)
      gl2lds16(ga + (size_t)(i * 32) * K, &As[buf][i * 32][0] + (size_t)tid * 8);
    const u16* gb = &B[(size_t)(n0 + s_r) * K + k0 + s_c * 8];
#pragma unroll
    for (int i = 0; i < BN / 32; i++)
      gl2lds16(gb + (size_t)(i * 32) * K, &Bs[buf][i * 32][0] + (size_t)tid * 8);
  };

  const f32x4 fz = {0.f, 0.f, 0.f, 0.f};
  f32x4 acc[FM][FN];
#pragma unroll
  for (int i = 0; i < FM; i++)
#pragma unroll
    for (int j = 0; j < FN; j++) acc[i][j] = fz;

  GSTAGE(0, 0);
  int buf = 0;
  const int nk = K >> 6;
  for (int t = 0; t < nk; ++t) {
    if (t + 1 < nk) {
      GSTAGE(buf ^ 1, (t + 1) * 64);
      if constexpr (NL == 6)
        asm volatile("s_waitcnt vmcnt(6)" ::: "memory");
      else if constexpr (NL == 7)
        asm volatile("s_waitcnt vmcnt(7)" ::: "memory");
      else
        asm volatile("s_waitcnt vmcnt(8)" ::: "memory");
    } else {
      asm volatile("s_waitcnt vmcnt(0)" ::: "memory");
    }
    __builtin_amdgcn_s_barrier();
#pragma unroll
    for (int kk = 0; kk < 2; kk++) {
      bf16x8 af[FM], bfr[FN];
#pragma unroll
      for (int i = 0; i < FM; i++)
        af[i] = *(const bf16x8*)&As[buf][wr + i * 16 + li]
                                   [((kk * 4 + lg) ^ rdsw) * 8];
#pragma unroll
      for (int j = 0; j < FN; j++)
        bfr[j] = *(const bf16x8*)&Bs[buf][wc + j * 16 + li]
                                    [((kk * 4 + lg) ^ rdsw) * 8];
      __builtin_amdgcn_s_setprio(1);
#pragma unroll
      for (int i = 0; i < FM; i++)
#pragma unroll
        for (int j = 0; j < FN; j++) acc[i][j] = mfma16(af[i], bfr[j], acc[i][j]);
      __builtin_amdgcn_s_setprio(0);
    }
    __builtin_amdgcn_s_barrier();
    buf ^= 1;
  }
#pragma unroll
  for (int i = 0; i < FM; i++)
#pragma unroll
    for (int j = 0; j < FN; j++)
#pragma unroll
      for (int r = 0; r < 4; r++) {
        const size_t idx =
            (size_t)(m0 + wr + i * 16 + lg * 4 + r) * N + n0 + wc + j * 16 + li;
        if constexpr (O16)
          ((u16*)Cv)[idx] = f2bf(acc[i][j][r]);
        else
          ((float*)Cv)[idx] = acc[i][j][r];
      }
}

// ---------------- fused RMSNorm + RoPE for 20 heads (16 q + 4 k) ------------
__global__ __launch_bounds__(256) void rmsropeqk(const u16* __restrict__ in,
                                                 const float* __restrict__ qg,
                                                 u16* __restrict__ qhb,
                                                 u16* __restrict__ khb, int S,
                                                 const float2* __restrict__ tbl) {
  const int w = threadIdx.x >> 6;
  const int t = threadIdx.x & 63;
  const int row = blockIdx.x * 4 + w;
  const int h = blockIdx.y;  // 0..19
  const bool isq = h < 16;
  const int col = isq ? h * 64 : 1024 + (h - 16) * 64;
  const float v = bf2f(in[(size_t)row * 1536 + col + t]);
  float ss = v * v;
#pragma unroll
  for (int m = 1; m < 64; m <<= 1) ss += __shfl_xor(ss, m);
  const float vn = v * rsqrtf(ss * (1.0f / 64.0f) + 1.1920929e-07f);
  const float partner = __shfl_xor(vn, 32);
  const int b = row / S;
  const int s = row - b * S;
  const float2 cs2 = tbl[s * 32 + (t & 31)];
  float o = (t < 32) ? (vn * cs2.x + partner * cs2.y)
                     : (vn * cs2.x - partner * cs2.y);
  if (isq) {
    o *= 0.18033688011112042f * qg[h];
    qhb[((size_t)(b * 16 + h) * S + s) * 64 + t] = f2bf(o);
  } else {
    khb[((size_t)(b * 4 + (h - 16)) * S + s) * 64 + t] = f2bf(o);
  }
}

// ---------------- V transpose via LDS ----------------
__global__ __launch_bounds__(256) void vcast2(const u16* __restrict__ qf,
                                              u16* __restrict__ vt, int S) {
  const int blk = blockIdx.x;
  const int sc = blk & 7;
  const int kv = (blk >> 3) & 3;
  const int b = blk >> 5;
  __shared__ u16 T[256][66];
  const int tid = threadIdx.x;
  const int dcol = tid & 63;
  const int w = tid >> 6;
  const u16* src =
      qf + (size_t)(b * S + sc * 256) * 1536 + 1280 + kv * 64 + dcol;
#pragma unroll 4
  for (int i = 0; i < 64; ++i) {
    const int sl = i * 4 + w;
    T[sl][dcol] = src[(size_t)sl * 1536];
  }
  __syncthreads();
  u16* dst = vt + (size_t)((b * 4 + kv) * 64) * S + sc * 256;
  const int l = tid & 63;
#pragma unroll 4
  for (int i = 0; i < 16; ++i) {
    const int drow = i * 4 + w;
    u16x4 v4;
    v4[0] = T[l * 4 + 0][drow];
    v4[1] = T[l * 4 + 1][drow];
    v4[2] = T[l * 4 + 2][drow];
    v4[3] = T[l * 4 + 3][drow];
    *(u16x4*)(dst + (size_t)drow * S + l * 4) = v4;
  }
}

// ---------------- flash attention v10: 32 q-rows/wave, shared K/V reads -----
// q-tile = 128 rows/block (4 waves x 32), KVBLK = 64. K/V LDS fragments are
// loaded once and feed BOTH q-groups -> LDS reads/row drop ~45%.
// grid 512 = 2 blocks/CU; heavy-first pairing t = i<256 ? 15-(i>>5) : (i>>5)-8
// gives every CU exactly 34 iterations. Max-free softmax (per-head bound).
__global__ __launch_bounds__(256, 2) void attn10(const u16* __restrict__ qh,
                                                 const u16* __restrict__ kh,
                                                 const u16* __restrict__ vt,
                                                 const float* __restrict__ qg,
                                                 u16* __restrict__ y, int S) {
  const int i = blockIdx.x;
  const int bh = i & 31;
  const int t = (i < 256) ? 15 - (i >> 5) : (i >> 5) - 8;
  const int h = bh & 15, b = bh >> 4;
  const int kvh = h >> 2;
  const int tid = threadIdx.x;
  const int wave = tid >> 6;
  const int lane = tid & 63;
  const int lg = lane >> 4, li = lane & 15;
  const int q0w = t * 128 + wave * 32;  // this wave's 32 q rows
  const float mrow = 11.541560327111707f * fabsf(qg[h]);

  const u16* qp = qh + ((size_t)(b * 16 + h) * S + q0w) * 64;
  const u16* kp = kh + (size_t)(b * 4 + kvh) * S * 64;
  const u16* vp = vt + (size_t)(b * 4 + kvh) * 64 * S;

  __shared__ __align__(16) u16 Ks[2][64][64];
  __shared__ __align__(16) u16 Vs[2][64][64];
  __shared__ __align__(16) u16 Ps[4][32][64];

  const int s_r0 = tid >> 3;
  const int s_c = (tid & 7) ^ ((tid >> 3) & 7);
  char* psrow0 = (char*)&Ps[wave][li][0];
  char* psrow1 = (char*)&Ps[wave][16 + li][0];
  const int swz = li & 7;
  const int rdsw = li & 7;
  const f32x4 minit = {-mrow, -mrow, -mrow, -mrow};
  const f32x4 fz = {0.f, 0.f, 0.f, 0.f};
  const u16x8 ones_u = {0x3F80, 0x3F80, 0x3F80, 0x3F80,
                        0x3F80, 0x3F80, 0x3F80, 0x3F80};
  const bf16x8 onesb = *(const bf16x8*)&ones_u;

#define STAGE(buf, kb)                                                        \
  {                                                                           \
    const u16* gk = kp + (size_t)((kb) + s_r0) * 64 + s_c * 8;                \
    gl2lds16(gk, &Ks[buf][0][0] + (size_t)tid * 8);                           \
    gl2lds16(gk + (size_t)32 * 64, &Ks[buf][32][0] + (size_t)tid * 8);        \
    const u16* gv = vp + (size_t)s_r0 * S + (kb) + s_c * 8;                   \
    gl2lds16(gv, &Vs[buf][0][0] + (size_t)tid * 8);                           \
    gl2lds16(gv + (size_t)32 * S, &Vs[buf][32][0] + (size_t)tid * 8);         \
  }

  STAGE(0, 0)
  bf16x8 qf0[2], qf1[2];
#pragma unroll
  for (int g = 0; g < 2; g++) {
    qf0[g] = *(const bf16x8*)&qp[(g * 16 + li) * 64 + lg * 8];
    qf1[g] = *(const bf16x8*)&qp[(g * 16 + li) * 64 + 32 + lg * 8];
  }

  f32x4 o[4][2];
#pragma unroll
  for (int j = 0; j < 4; j++)
#pragma unroll
    for (int g = 0; g < 2; g++) o[j][g] = fz;
  f32x4 lsum[2] = {fz, fz};

  const int nkv = 2 * t + 2;
  int buf = 0;
  for (int tt = 0; tt < nkv; ++tt) {
    if (tt + 1 < nkv) {
      STAGE(buf ^ 1, (tt + 1) * 64)
      asm volatile("s_waitcnt vmcnt(4)" ::: "memory");
    } else {
      asm volatile("s_waitcnt vmcnt(0)" ::: "memory");
    }
    __builtin_amdgcn_s_barrier();
    const int kb = tt * 64;
    // --- S^T = K · Q^T: K fragments shared by both q-groups ---
    f32x4 s[4][2];
    __builtin_amdgcn_s_setprio(1);
#pragma unroll
    for (int t4 = 0; t4 < 4; t4++) {
      const bf16x8 ka =
          *(const bf16x8*)&Ks[buf][t4 * 16 + li][((lg) ^ rdsw) * 8];
      const bf16x8 kc =
          *(const bf16x8*)&Ks[buf][t4 * 16 + li][((lg + 4) ^ rdsw) * 8];
#pragma unroll
      for (int g = 0; g < 2; g++) {
        s[t4][g] = mfma16(ka, qf0[g], minit);
        s[t4][g] = mfma16(kc, qf1[g], s[t4][g]);
      }
    }
    __builtin_amdgcn_s_setprio(0);
    // --- exp2 softmax (max-free); mask only near the diagonal ---
    float pv[2][16];
    if (kb + 63 <= q0w) {  // interior: all keys <= every q row of this wave
#pragma unroll
      for (int t4 = 0; t4 < 4; t4++)
#pragma unroll
        for (int g = 0; g < 2; g++)
#pragma unroll
          for (int r = 0; r < 4; r++)
            pv[g][t4 * 4 + r] = exp2f(s[t4][g][r]);
    } else {
#pragma unroll
      for (int t4 = 0; t4 < 4; t4++)
#pragma unroll
        for (int g = 0; g < 2; g++)
#pragma unroll
          for (int r = 0; r < 4; r++) {
            const int key = kb + t4 * 16 + lg * 4 + r;
            const int qrow = q0w + g * 16 + li;
            pv[g][t4 * 4 + r] = exp2f(key > qrow ? -1e30f : s[t4][g][r]);
          }
    }
    // --- P -> LDS (packed bf16, swizzled 8B blocks), per group ---
#pragma unroll
    for (int t4 = 0; t4 < 4; t4++) {
      const int c8 = (t4 * 4 + lg) ^ (swz << 1);
      uint2 w0, w1;
      w0.x = cvtpk(pv[0][t4 * 4 + 0], pv[0][t4 * 4 + 1]);
      w0.y = cvtpk(pv[0][t4 * 4 + 2], pv[0][t4 * 4 + 3]);
      w1.x = cvtpk(pv[1][t4 * 4 + 0], pv[1][t4 * 4 + 1]);
      w1.y = cvtpk(pv[1][t4 * 4 + 2], pv[1][t4 * 4 + 3]);
      *(uint2*)(psrow0 + c8 * 8) = w0;
      *(uint2*)(psrow1 + c8 * 8) = w1;
    }
    bf16x8 pa0[2], pa1[2];
    pa0[0] = *(const bf16x8*)(psrow0 + ((lg + 0) ^ swz) * 16);
    pa1[0] = *(const bf16x8*)(psrow0 + ((lg + 4) ^ swz) * 16);
    pa0[1] = *(const bf16x8*)(psrow1 + ((lg + 0) ^ swz) * 16);
    pa1[1] = *(const bf16x8*)(psrow1 + ((lg + 4) ^ swz) * 16);
    // --- PV: V fragments shared by both q-groups ---
    __builtin_amdgcn_s_setprio(1);
#pragma unroll
    for (int j = 0; j < 4; j++) {
      const bf16x8 v0 =
          *(const bf16x8*)&Vs[buf][j * 16 + li][((lg) ^ rdsw) * 8];
      const bf16x8 v1 =
          *(const bf16x8*)&Vs[buf][j * 16 + li][((lg + 4) ^ rdsw) * 8];
#pragma unroll
      for (int g = 0; g < 2; g++) {
        o[j][g] = mfma16(pa0[g], v0, o[j][g]);
        o[j][g] = mfma16(pa1[g], v1, o[j][g]);
      }
    }
#pragma unroll
    for (int g = 0; g < 2; g++) {
      lsum[g] = mfma16(pa0[g], onesb, lsum[g]);
      lsum[g] = mfma16(pa1[g], onesb, lsum[g]);
    }
    __builtin_amdgcn_s_setprio(0);
    __builtin_amdgcn_s_barrier();
    buf ^= 1;
  }
#undef STAGE
#pragma unroll
  for (int g = 0; g < 2; g++)
#pragma unroll
    for (int j = 0; j < 4; j++)
#pragma unroll
      for (int r = 0; r < 4; r++)
        y[((size_t)(b * S + q0w + g * 16 + lg * 4 + r)) * 1024 + h * 64 +
          j * 16 + li] = f2bf(o[j][g][r] / lsum[g][r]);
}

extern "C" void kernel_launch(void* const* d_in, const int* in_sizes, int n_in,
                              void* d_out, int out_size, void* d_ws, size_t ws_size,
                              hipStream_t stream) {
  const float* x  = (const float*)d_in[0];
  const float* Wq = (const float*)d_in[1];
  const float* Wk = (const float*)d_in[2];
  const float* Wv = (const float*)d_in[3];
  const float* Wp = (const float*)d_in[4];
  const float* qg = (const float*)d_in[5];
  float* out = (float*)d_out;

  const int S = 2048;
  char* ws = (char*)d_ws;
  u16*    xb    = (u16*)(ws + 0);          // 8 MB
  u16*    wallb = (u16*)(ws + 8388608);    // 3 MB
  u16*    wpb   = (u16*)(ws + 11534336);   // 2 MB
  float2* tbl   = (float2*)(ws + 13631488);// 512 KB
  u16*    qf    = (u16*)(ws + 14155776);   // [4096][1536] bf16 (12 MB)
  u16*    qhb   = (u16*)(ws + 26738688);   // 8 MB
  u16*    khb   = (u16*)(ws + 35127296);   // 2 MB
  u16*    vtb   = (u16*)(ws + 37224448);   // 2 MB
  u16*    yb    = (u16*)(ws + 39321600);   // 8 MB -> 47710208
  if (ws_size < 47710208) return;

  megacast<<<3584, 256, 0, stream>>>(x, Wq, Wk, Wv, Wp, xb, wallb, wpb, tbl);

  gemm_bt<128, 96, true><<<dim3(16, 32), 256, 0, stream>>>(xb, wallb, qf,
                                                           4096, 1536, 1024);

  rmsropeqk<<<dim3(1024, 20), 256, 0, stream>>>(qf, qg, qhb, khb, S, tbl);
  vcast2<<<64, 256, 0, stream>>>(qf, vtb, S);

  attn10<<<512, 256, 0, stream>>>(qhb, khb, vtb, qg, yb, S);

  gemm_bt<64, 128, false><<<dim3(8, 64), 256, 0, stream>>>(yb, wpb, out,
                                                           4096, 1024, 1024);
}

// Round 13
// 113.839 us; speedup vs baseline: 1.0353x; 1.0253x over previous
//
#include <hip/hip_runtime.h>

typedef unsigned short u16;
typedef __bf16 bf16_t;
typedef bf16_t bf16x8 __attribute__((ext_vector_type(8)));
typedef float f32x4 __attribute__((ext_vector_type(4)));
typedef u16 u16x8 __attribute__((ext_vector_type(8)));
typedef u16 u16x4 __attribute__((ext_vector_type(4)));

__device__ __forceinline__ u16 f2bf(float f) {
  unsigned u = __float_as_uint(f);
  u += 0x7fffu + ((u >> 16) & 1u);
  return (u16)(u >> 16);
}

__device__ __forceinline__ float bf2f(u16 u) {
  return __uint_as_float((unsigned)u << 16);
}

__device__ __forceinline__ unsigned cvtpk(float lo, float hi) {
  unsigned r;
  asm("v_cvt_pk_bf16_f32 %0, %1, %2" : "=v"(r) : "v"(lo), "v"(hi));
  return r;
}

__device__ __forceinline__ f32x4 mfma16(bf16x8 a, bf16x8 b, f32x4 c) {
  return __builtin_amdgcn_mfma_f32_16x16x32_bf16(a, b, c, 0, 0, 0);
}

__device__ __forceinline__ void gl2lds16(const u16* g, u16* l) {
  __builtin_amdgcn_global_load_lds(
      (__attribute__((address_space(1))) void*)(u16*)g,
      (__attribute__((address_space(3))) void*)l, 16, 0, 0);
}

__device__ __forceinline__ void cast8(const float* __restrict__ in,
                                      u16* __restrict__ out, int i) {
  float4 a = *(const float4*)&in[i];
  float4 b = *(const float4*)&in[i + 4];
  uint4 o;
  o.x = cvtpk(a.x, a.y);
  o.y = cvtpk(a.z, a.w);
  o.z = cvtpk(b.x, b.y);
  o.w = cvtpk(b.z, b.w);
  *(uint4*)&out[i] = o;
}

// ---------------- megacast: all f32->bf16 casts + trig table, one launch ----
__global__ __launch_bounds__(256) void megacast(
    const float* __restrict__ x, const float* __restrict__ Wq,
    const float* __restrict__ Wk, const float* __restrict__ Wv,
    const float* __restrict__ Wp, u16* __restrict__ xb,
    u16* __restrict__ wallb, u16* __restrict__ wpb,
    float2* __restrict__ tbl) {
  const int blk = blockIdx.x;
  const int tid = threadIdx.x;
  if (blk < 2048) {
    cast8(x, xb, (blk * 256 + tid) * 8);
  } else if (blk < 2560) {
    cast8(Wq, wallb, ((blk - 2048) * 256 + tid) * 8);
  } else if (blk < 2688) {
    cast8(Wk, wallb + 1048576, ((blk - 2560) * 256 + tid) * 8);
  } else if (blk < 2816) {
    cast8(Wv, wallb + 1310720, ((blk - 2688) * 256 + tid) * 8);
  } else if (blk < 3328) {
    cast8(Wp, wpb, ((blk - 2816) * 256 + tid) * 8);
  } else {
    const int idx = (blk - 3328) * 256 + tid;  // < 65536
    const int s = idx >> 5, i = idx & 31;
    float inv = exp2f(-(float)i * (13.287712379549449f / 32.0f));
    float fr = (float)s * inv;
    float sn, cs;
    sincosf(fr, &sn, &cs);
    tbl[idx] = make_float2(cs, sn);
  }
}

// ---------------- GEMM: C[M][N] = A[M][K] * B[N][K]^T, tiled BMxBN ----------
template <int BM, int BN, bool O16>
__global__ __launch_bounds__(256) void gemm_bt(const u16* __restrict__ A,
                                               const u16* __restrict__ B,
                                               void* __restrict__ Cv,
                                               int M, int N, int K) {
  constexpr int FM = BM / 32;
  constexpr int FN = BN / 32;
  constexpr int NL = (BM + BN) / 32;
  __shared__ __align__(16) u16 As[2][BM][64];
  __shared__ __align__(16) u16 Bs[2][BN][64];
  const int tid = threadIdx.x;
  const int lane = tid & 63;
  const int lg = lane >> 4, li = lane & 15;
  const int wave = tid >> 6;
  const int wr = (wave >> 1) * (BM / 2), wc = (wave & 1) * (BN / 2);
  const int m0 = blockIdx.y * BM, n0 = blockIdx.x * BN;

  const int s_r = tid >> 3;
  const int s_c = (tid & 7) ^ ((tid >> 3) & 7);
  const int rdsw = li & 7;

  auto GSTAGE = [&](int buf, int k0) {
    const u16* ga = &A[(size_t)(m0 + s_r) * K + k0 + s_c * 8];
#pragma unroll
    for (int i = 0; i < BM / 32; i++)
      gl2lds16(ga + (size_t)(i * 32) * K, &As[buf][i * 32][0] + (size_t)tid * 8);
    const u16* gb = &B[(size_t)(n0 + s_r) * K + k0 + s_c * 8];
#pragma unroll
    for (int i = 0; i < BN / 32; i++)
      gl2lds16(gb + (size_t)(i * 32) * K, &Bs[buf][i * 32][0] + (size_t)tid * 8);
  };

  const f32x4 fz = {0.f, 0.f, 0.f, 0.f};
  f32x4 acc[FM][FN];
#pragma unroll
  for (int i = 0; i < FM; i++)
#pragma unroll
    for (int j = 0; j < FN; j++) acc[i][j] = fz;

  GSTAGE(0, 0);
  int buf = 0;
  const int nk = K >> 6;
  for (int t = 0; t < nk; ++t) {
    if (t + 1 < nk) {
      GSTAGE(buf ^ 1, (t + 1) * 64);
      if constexpr (NL == 6)
        asm volatile("s_waitcnt vmcnt(6)" ::: "memory");
      else if constexpr (NL == 7)
        asm volatile("s_waitcnt vmcnt(7)" ::: "memory");
      else
        asm volatile("s_waitcnt vmcnt(8)" ::: "memory");
    } else {
      asm volatile("s_waitcnt vmcnt(0)" ::: "memory");
    }
    __builtin_amdgcn_s_barrier();
#pragma unroll
    for (int kk = 0; kk < 2; kk++) {
      bf16x8 af[FM], bfr[FN];
#pragma unroll
      for (int i = 0; i < FM; i++)
        af[i] = *(const bf16x8*)&As[buf][wr + i * 16 + li]
                                   [((kk * 4 + lg) ^ rdsw) * 8];
#pragma unroll
      for (int j = 0; j < FN; j++)
        bfr[j] = *(const bf16x8*)&Bs[buf][wc + j * 16 + li]
                                    [((kk * 4 + lg) ^ rdsw) * 8];
      __builtin_amdgcn_s_setprio(1);
#pragma unroll
      for (int i = 0; i < FM; i++)
#pragma unroll
        for (int j = 0; j < FN; j++) acc[i][j] = mfma16(af[i], bfr[j], acc[i][j]);
      __builtin_amdgcn_s_setprio(0);
    }
    __builtin_amdgcn_s_barrier();
    buf ^= 1;
  }
#pragma unroll
  for (int i = 0; i < FM; i++)
#pragma unroll
    for (int j = 0; j < FN; j++)
#pragma unroll
      for (int r = 0; r < 4; r++) {
        const size_t idx =
            (size_t)(m0 + wr + i * 16 + lg * 4 + r) * N + n0 + wc + j * 16 + li;
        if constexpr (O16)
          ((u16*)Cv)[idx] = f2bf(acc[i][j][r]);
        else
          ((float*)Cv)[idx] = acc[i][j][r];
      }
}

// ---------------- fused RMSNorm+RoPE (20 heads) + V transpose, one launch ---
// idx < 20480: rmsrope for head idx>>10, row-block idx&1023.
// idx >= 20480: V transpose chunk (64 blocks).
__global__ __launch_bounds__(256) void posttrans(const u16* __restrict__ qf,
                                                 const float* __restrict__ qg,
                                                 u16* __restrict__ qhb,
                                                 u16* __restrict__ khb,
                                                 u16* __restrict__ vtb, int S,
                                                 const float2* __restrict__ tbl) {
  const int idx = blockIdx.x;
  const int tid = threadIdx.x;
  if (idx < 20480) {
    const int h = idx >> 10;       // 0..19
    const int rowblk = idx & 1023;
    const int w = tid >> 6;
    const int t = tid & 63;
    const int row = rowblk * 4 + w;
    const bool isq = h < 16;
    const int col = isq ? h * 64 : 1024 + (h - 16) * 64;
    const float v = bf2f(qf[(size_t)row * 1536 + col + t]);
    float ss = v * v;
#pragma unroll
    for (int m = 1; m < 64; m <<= 1) ss += __shfl_xor(ss, m);
    const float vn = v * rsqrtf(ss * (1.0f / 64.0f) + 1.1920929e-07f);
    const float partner = __shfl_xor(vn, 32);
    const int b = row / S;
    const int s = row - b * S;
    const float2 cs2 = tbl[s * 32 + (t & 31)];
    float o = (t < 32) ? (vn * cs2.x + partner * cs2.y)
                       : (vn * cs2.x - partner * cs2.y);
    if (isq) {
      o *= 0.18033688011112042f * qg[h];
      qhb[((size_t)(b * 16 + h) * S + s) * 64 + t] = f2bf(o);
    } else {
      khb[((size_t)(b * 4 + (h - 16)) * S + s) * 64 + t] = f2bf(o);
    }
  } else {
    const int blk = idx - 20480;   // 0..63
    const int sc = blk & 7;
    const int kv = (blk >> 3) & 3;
    const int b = blk >> 5;
    __shared__ u16 T[256][66];
    const int dcol = tid & 63;
    const int w = tid >> 6;
    const u16* src =
        qf + (size_t)(b * S + sc * 256) * 1536 + 1280 + kv * 64 + dcol;
#pragma unroll 4
    for (int i = 0; i < 64; ++i) {
      const int sl = i * 4 + w;
      T[sl][dcol] = src[(size_t)sl * 1536];
    }
    __syncthreads();
    u16* dst = vtb + (size_t)((b * 4 + kv) * 64) * S + sc * 256;
    const int l = tid & 63;
#pragma unroll 4
    for (int i = 0; i < 16; ++i) {
      const int drow = i * 4 + w;
      u16x4 v4;
      v4[0] = T[l * 4 + 0][drow];
      v4[1] = T[l * 4 + 1][drow];
      v4[2] = T[l * 4 + 2][drow];
      v4[3] = T[l * 4 + 3][drow];
      *(u16x4*)(dst + (size_t)drow * S + l * 4) = v4;
    }
  }
}

// ---------------- flash attention v8 (known-best): max-free softmax ---------
// Scores (log2 domain) provably <= 11.5416*|gain_h| since ||q^||,||k^|| <= 8.
// grid 1024: bh = idx&31, g = idx>>5; per-CU qb set {31-d,16+d,15-d,d}.
__global__ __launch_bounds__(256) void attn8(const u16* __restrict__ qh,
                                             const u16* __restrict__ kh,
                                             const u16* __restrict__ vt,
                                             const float* __restrict__ qg,
                                             u16* __restrict__ y, int S) {
  const int bh = blockIdx.x & 31;
  const int g = blockIdx.x >> 5;
  const int d = g & 7, u = g >> 3;
  const int qb = (u == 0) ? 31 - d : (u == 1) ? 16 + d : (u == 2) ? 15 - d : d;
  const int h = bh & 15, b = bh >> 4;
  const int kvh = h >> 2;
  const int tid = threadIdx.x;
  const int wave = tid >> 6;
  const int lane = tid & 63;
  const int lg = lane >> 4, li = lane & 15;
  const int q0 = qb * 64 + wave * 16;
  const int qrow = q0 + li;
  const float mrow = 11.541560327111707f * fabsf(qg[h]);

  const u16* qp = qh + ((size_t)(b * 16 + h) * S + q0) * 64;
  const u16* kp = kh + (size_t)(b * 4 + kvh) * S * 64;
  const u16* vp = vt + (size_t)(b * 4 + kvh) * 64 * S;

  __shared__ __align__(16) u16 Ks[2][64][64];
  __shared__ __align__(16) u16 Vs[2][64][64];
  __shared__ __align__(16) u16 Ps[4][16][64];

  const int s_r0 = tid >> 3;
  const int s_c = (tid & 7) ^ ((tid >> 3) & 7);
  char* psrow = (char*)&Ps[wave][li][0];
  const int swz = li & 7;
  const int rdsw = li & 7;
  const f32x4 minit = {-mrow, -mrow, -mrow, -mrow};
  const f32x4 fz = {0.f, 0.f, 0.f, 0.f};
  const u16x8 ones_u = {0x3F80, 0x3F80, 0x3F80, 0x3F80,
                        0x3F80, 0x3F80, 0x3F80, 0x3F80};
  const bf16x8 onesb = *(const bf16x8*)&ones_u;

#define STAGE(buf, kb)                                                        \
  {                                                                           \
    const u16* gk = kp + (size_t)((kb) + s_r0) * 64 + s_c * 8;                \
    gl2lds16(gk, &Ks[buf][0][0] + (size_t)tid * 8);                           \
    gl2lds16(gk + (size_t)32 * 64, &Ks[buf][32][0] + (size_t)tid * 8);        \
    const u16* gv = vp + (size_t)s_r0 * S + (kb) + s_c * 8;                   \
    gl2lds16(gv, &Vs[buf][0][0] + (size_t)tid * 8);                           \
    gl2lds16(gv + (size_t)32 * S, &Vs[buf][32][0] + (size_t)tid * 8);         \
  }

  STAGE(0, 0)
  const bf16x8 qf0 = *(const bf16x8*)&qp[li * 64 + lg * 8];
  const bf16x8 qf1 = *(const bf16x8*)&qp[li * 64 + 32 + lg * 8];

  f32x4 o[4];
#pragma unroll
  for (int j = 0; j < 4; j++) o[j] = fz;
  f32x4 lsum = fz;

  int buf = 0;
  for (int tt = 0; tt <= qb; ++tt) {
    if (tt < qb) {
      STAGE(buf ^ 1, (tt + 1) * 64)
      asm volatile("s_waitcnt vmcnt(4)" ::: "memory");
    } else {
      asm volatile("s_waitcnt vmcnt(0)" ::: "memory");
    }
    __builtin_amdgcn_s_barrier();
    const int kb = tt * 64;
    f32x4 s[4];
    __builtin_amdgcn_s_setprio(1);
#pragma unroll
    for (int t = 0; t < 4; t++) {
      const bf16x8 ka =
          *(const bf16x8*)&Ks[buf][t * 16 + li][((lg) ^ rdsw) * 8];
      const bf16x8 kc =
          *(const bf16x8*)&Ks[buf][t * 16 + li][((lg + 4) ^ rdsw) * 8];
      s[t] = mfma16(ka, qf0, minit);
      s[t] = mfma16(kc, qf1, s[t]);
    }
    __builtin_amdgcn_s_setprio(0);
    float pv[16];
    if (tt < qb) {
#pragma unroll
      for (int t = 0; t < 4; t++)
#pragma unroll
        for (int r = 0; r < 4; r++) pv[t * 4 + r] = exp2f(s[t][r]);
    } else {
#pragma unroll
      for (int t = 0; t < 4; t++)
#pragma unroll
        for (int r = 0; r < 4; r++) {
          const float x =
              (kb + t * 16 + lg * 4 + r > qrow) ? -1e30f : s[t][r];
          pv[t * 4 + r] = exp2f(x);
        }
    }
#pragma unroll
    for (int t = 0; t < 4; t++) {
      uint2 w;
      w.x = cvtpk(pv[t * 4 + 0], pv[t * 4 + 1]);
      w.y = cvtpk(pv[t * 4 + 2], pv[t * 4 + 3]);
      const int c8 = (t * 4 + lg) ^ (swz << 1);
      *(uint2*)(psrow + c8 * 8) = w;
    }
    const bf16x8 pa0 = *(const bf16x8*)(psrow + ((lg + 0) ^ swz) * 16);
    const bf16x8 pa1 = *(const bf16x8*)(psrow + ((lg + 4) ^ swz) * 16);
    __builtin_amdgcn_s_setprio(1);
#pragma unroll
    for (int j = 0; j < 4; j++) {
      const bf16x8 v0 =
          *(const bf16x8*)&Vs[buf][j * 16 + li][((lg) ^ rdsw) * 8];
      const bf16x8 v1 =
          *(const bf16x8*)&Vs[buf][j * 16 + li][((lg + 4) ^ rdsw) * 8];
      o[j] = mfma16(pa0, v0, o[j]);
      o[j] = mfma16(pa1, v1, o[j]);
    }
    lsum = mfma16(pa0, onesb, lsum);
    lsum = mfma16(pa1, onesb, lsum);
    __builtin_amdgcn_s_setprio(0);
    __builtin_amdgcn_s_barrier();
    buf ^= 1;
  }
#undef STAGE
#pragma unroll
  for (int j = 0; j < 4; j++)
#pragma unroll
    for (int r = 0; r < 4; r++)
      y[((size_t)(b * S + q0 + lg * 4 + r)) * 1024 + h * 64 + j * 16 + li] =
          f2bf(o[j][r] / lsum[r]);
}

extern "C" void kernel_launch(void* const* d_in, const int* in_sizes, int n_in,
                              void* d_out, int out_size, void* d_ws, size_t ws_size,
                              hipStream_t stream) {
  const float* x  = (const float*)d_in[0];
  const float* Wq = (const float*)d_in[1];
  const float* Wk = (const float*)d_in[2];
  const float* Wv = (const float*)d_in[3];
  const float* Wp = (const float*)d_in[4];
  const float* qg = (const float*)d_in[5];
  float* out = (float*)d_out;

  const int S = 2048;
  char* ws = (char*)d_ws;
  u16*    xb    = (u16*)(ws + 0);          // 8 MB
  u16*    wallb = (u16*)(ws + 8388608);    // 3 MB
  u16*    wpb   = (u16*)(ws + 11534336);   // 2 MB
  float2* tbl   = (float2*)(ws + 13631488);// 512 KB
  u16*    qf    = (u16*)(ws + 14155776);   // [4096][1536] bf16 (12 MB)
  u16*    qhb   = (u16*)(ws + 26738688);   // 8 MB
  u16*    khb   = (u16*)(ws + 35127296);   // 2 MB
  u16*    vtb   = (u16*)(ws + 37224448);   // 2 MB
  u16*    yb    = (u16*)(ws + 39321600);   // 8 MB -> 47710208
  if (ws_size < 47710208) return;

  megacast<<<3584, 256, 0, stream>>>(x, Wq, Wk, Wv, Wp, xb, wallb, wpb, tbl);

  // fused QKV projection: 128x64 tile -> 768 blocks = exactly 3/CU
  gemm_bt<128, 64, true><<<dim3(24, 32), 256, 0, stream>>>(xb, wallb, qf,
                                                           4096, 1536, 1024);

  // RMSNorm+RoPE (20 heads) + V transpose in one dispatch
  posttrans<<<20544, 256, 0, stream>>>(qf, qg, qhb, khb, vtb, S, tbl);

  attn8<<<1024, 256, 0, stream>>>(qhb, khb, vtb, qg, yb, S);

  // output projection: 64x128 tile -> 512 blocks = 2/CU
  gemm_bt<64, 128, false><<<dim3(8, 64), 256, 0, stream>>>(yb, wpb, out,
                                                           4096, 1024, 1024);
}

// Round 15
// 112.598 us; speedup vs baseline: 1.0468x; 1.0110x over previous
//
#include <hip/hip_runtime.h>

typedef unsigned short u16;
typedef __bf16 bf16_t;
typedef bf16_t bf16x8 __attribute__((ext_vector_type(8)));
typedef float f32x4 __attribute__((ext_vector_type(4)));
typedef u16 u16x8 __attribute__((ext_vector_type(8)));
typedef u16 u16x4 __attribute__((ext_vector_type(4)));

__device__ __forceinline__ u16 f2bf(float f) {
  unsigned u = __float_as_uint(f);
  u += 0x7fffu + ((u >> 16) & 1u);
  return (u16)(u >> 16);
}

__device__ __forceinline__ float bf2f(u16 u) {
  return __uint_as_float((unsigned)u << 16);
}

__device__ __forceinline__ unsigned cvtpk(float lo, float hi) {
  unsigned r;
  asm("v_cvt_pk_bf16_f32 %0, %1, %2" : "=v"(r) : "v"(lo), "v"(hi));
  return r;
}

__device__ __forceinline__ f32x4 mfma16(bf16x8 a, bf16x8 b, f32x4 c) {
  return __builtin_amdgcn_mfma_f32_16x16x32_bf16(a, b, c, 0, 0, 0);
}

__device__ __forceinline__ void gl2lds16(const u16* g, u16* l) {
  __builtin_amdgcn_global_load_lds(
      (__attribute__((address_space(1))) void*)(u16*)g,
      (__attribute__((address_space(3))) void*)l, 16, 0, 0);
}

__device__ __forceinline__ void cast8(const float* __restrict__ in,
                                      u16* __restrict__ out, int i) {
  float4 a = *(const float4*)&in[i];
  float4 b = *(const float4*)&in[i + 4];
  uint4 o;
  o.x = cvtpk(a.x, a.y);
  o.y = cvtpk(a.z, a.w);
  o.z = cvtpk(b.x, b.y);
  o.w = cvtpk(b.z, b.w);
  *(uint4*)&out[i] = o;
}

// ---------------- megacast: all f32->bf16 casts + trig table, one launch ----
__global__ __launch_bounds__(256) void megacast(
    const float* __restrict__ x, const float* __restrict__ Wq,
    const float* __restrict__ Wk, const float* __restrict__ Wv,
    const float* __restrict__ Wp, u16* __restrict__ xb,
    u16* __restrict__ wallb, u16* __restrict__ wpb,
    float2* __restrict__ tbl) {
  const int blk = blockIdx.x;
  const int tid = threadIdx.x;
  if (blk < 2048) {
    cast8(x, xb, (blk * 256 + tid) * 8);
  } else if (blk < 2560) {
    cast8(Wq, wallb, ((blk - 2048) * 256 + tid) * 8);
  } else if (blk < 2688) {
    cast8(Wk, wallb + 1048576, ((blk - 2560) * 256 + tid) * 8);
  } else if (blk < 2816) {
    cast8(Wv, wallb + 1310720, ((blk - 2688) * 256 + tid) * 8);
  } else if (blk < 3328) {
    cast8(Wp, wpb, ((blk - 2816) * 256 + tid) * 8);
  } else {
    const int idx = (blk - 3328) * 256 + tid;  // < 65536
    const int s = idx >> 5, i = idx & 31;
    float inv = exp2f(-(float)i * (13.287712379549449f / 32.0f));
    float fr = (float)s * inv;
    float sn, cs;
    sincosf(fr, &sn, &cs);
    tbl[idx] = make_float2(cs, sn);
  }
}

// ---------------- GEMM: C[M][N] = A[M][K] * B[N][K]^T, tiled BMxBN ----------
template <int BM, int BN, bool O16>
__global__ __launch_bounds__(256) void gemm_bt(const u16* __restrict__ A,
                                               const u16* __restrict__ B,
                                               void* __restrict__ Cv,
                                               int M, int N, int K) {
  constexpr int FM = BM / 32;
  constexpr int FN = BN / 32;
  constexpr int NL = (BM + BN) / 32;
  __shared__ __align__(16) u16 As[2][BM][64];
  __shared__ __align__(16) u16 Bs[2][BN][64];
  const int tid = threadIdx.x;
  const int lane = tid & 63;
  const int lg = lane >> 4, li = lane & 15;
  const int wave = tid >> 6;
  const int wr = (wave >> 1) * (BM / 2), wc = (wave & 1) * (BN / 2);
  const int m0 = blockIdx.y * BM, n0 = blockIdx.x * BN;

  const int s_r = tid >> 3;
  const int s_c = (tid & 7) ^ ((tid >> 3) & 7);
  const int rdsw = li & 7;

  auto GSTAGE = [&](int buf, int k0) {
    const u16* ga = &A[(size_t)(m0 + s_r) * K + k0 + s_c * 8];
#pragma unroll
    for (int i = 0; i < BM / 32; i++)
      gl2lds16(ga + (size_t)(i * 32) * K, &As[buf][i * 32][0] + (size_t)tid * 8);
    const u16* gb = &B[(size_t)(n0 + s_r) * K + k0 + s_c * 8];
#pragma unroll
    for (int i = 0; i < BN / 32; i++)
      gl2lds16(gb + (size_t)(i * 32) * K, &Bs[buf][i * 32][0] + (size_t)tid * 8);
  };

  const f32x4 fz = {0.f, 0.f, 0.f, 0.f};
  f32x4 acc[FM][FN];
#pragma unroll
  for (int i = 0; i < FM; i++)
#pragma unroll
    for (int j = 0; j < FN; j++) acc[i][j] = fz;

  GSTAGE(0, 0);
  int buf = 0;
  const int nk = K >> 6;
  for (int t = 0; t < nk; ++t) {
    if (t + 1 < nk) {
      GSTAGE(buf ^ 1, (t + 1) * 64);
      if constexpr (NL == 6)
        asm volatile("s_waitcnt vmcnt(6)" ::: "memory");
      else if constexpr (NL == 7)
        asm volatile("s_waitcnt vmcnt(7)" ::: "memory");
      else
        asm volatile("s_waitcnt vmcnt(8)" ::: "memory");
    } else {
      asm volatile("s_waitcnt vmcnt(0)" ::: "memory");
    }
    __builtin_amdgcn_s_barrier();
#pragma unroll
    for (int kk = 0; kk < 2; kk++) {
      bf16x8 af[FM], bfr[FN];
#pragma unroll
      for (int i = 0; i < FM; i++)
        af[i] = *(const bf16x8*)&As[buf][wr + i * 16 + li]
                                   [((kk * 4 + lg) ^ rdsw) * 8];
#pragma unroll
      for (int j = 0; j < FN; j++)
        bfr[j] = *(const bf16x8*)&Bs[buf][wc + j * 16 + li]
                                    [((kk * 4 + lg) ^ rdsw) * 8];
      __builtin_amdgcn_s_setprio(1);
#pragma unroll
      for (int i = 0; i < FM; i++)
#pragma unroll
        for (int j = 0; j < FN; j++) acc[i][j] = mfma16(af[i], bfr[j], acc[i][j]);
      __builtin_amdgcn_s_setprio(0);
    }
    __builtin_amdgcn_s_barrier();
    buf ^= 1;
  }
#pragma unroll
  for (int i = 0; i < FM; i++)
#pragma unroll
    for (int j = 0; j < FN; j++)
#pragma unroll
      for (int r = 0; r < 4; r++) {
        const size_t idx =
            (size_t)(m0 + wr + i * 16 + lg * 4 + r) * N + n0 + wc + j * 16 + li;
        if constexpr (O16)
          ((u16*)Cv)[idx] = f2bf(acc[i][j][r]);
        else
          ((float*)Cv)[idx] = acc[i][j][r];
      }
}

// ---------------- fused RMSNorm+RoPE (20 heads) + V transpose, one launch ---
__global__ __launch_bounds__(256) void posttrans(const u16* __restrict__ qf,
                                                 const float* __restrict__ qg,
                                                 u16* __restrict__ qhb,
                                                 u16* __restrict__ khb,
                                                 u16* __restrict__ vtb, int S,
                                                 const float2* __restrict__ tbl) {
  const int idx = blockIdx.x;
  const int tid = threadIdx.x;
  if (idx < 20480) {
    const int h = idx >> 10;       // 0..19
    const int rowblk = idx & 1023;
    const int w = tid >> 6;
    const int t = tid & 63;
    const int row = rowblk * 4 + w;
    const bool isq = h < 16;
    const int col = isq ? h * 64 : 1024 + (h - 16) * 64;
    const float v = bf2f(qf[(size_t)row * 1536 + col + t]);
    float ss = v * v;
#pragma unroll
    for (int m = 1; m < 64; m <<= 1) ss += __shfl_xor(ss, m);
    const float vn = v * rsqrtf(ss * (1.0f / 64.0f) + 1.1920929e-07f);
    const float partner = __shfl_xor(vn, 32);
    const int b = row / S;
    const int s = row - b * S;
    const float2 cs2 = tbl[s * 32 + (t & 31)];
    float o = (t < 32) ? (vn * cs2.x + partner * cs2.y)
                       : (vn * cs2.x - partner * cs2.y);
    if (isq) {
      o *= 0.18033688011112042f * qg[h];
      qhb[((size_t)(b * 16 + h) * S + s) * 64 + t] = f2bf(o);
    } else {
      khb[((size_t)(b * 4 + (h - 16)) * S + s) * 64 + t] = f2bf(o);
    }
  } else {
    const int blk = idx - 20480;   // 0..63
    const int sc = blk & 7;
    const int kv = (blk >> 3) & 3;
    const int b = blk >> 5;
    __shared__ u16 T[256][66];
    const int dcol = tid & 63;
    const int w = tid >> 6;
    const u16* src =
        qf + (size_t)(b * S + sc * 256) * 1536 + 1280 + kv * 64 + dcol;
#pragma unroll 4
    for (int i = 0; i < 64; ++i) {
      const int sl = i * 4 + w;
      T[sl][dcol] = src[(size_t)sl * 1536];
    }
    __syncthreads();
    u16* dst = vtb + (size_t)((b * 4 + kv) * 64) * S + sc * 256;
    const int l = tid & 63;
#pragma unroll 4
    for (int i = 0; i < 16; ++i) {
      const int drow = i * 4 + w;
      u16x4 v4;
      v4[0] = T[l * 4 + 0][drow];
      v4[1] = T[l * 4 + 1][drow];
      v4[2] = T[l * 4 + 2][drow];
      v4[3] = T[l * 4 + 3][drow];
      *(u16x4*)(dst + (size_t)drow * S + l * 4) = v4;
    }
  }
}

// ---------------- flash attention v13: in-register P, corrected butterfly ---
// O^T = V^T * P^T. P^T B-frags built with 4x v_permlane16_swap; the induced
// content permutation f = (swap key-bits 3,4) is absorbed by permuting the
// K staging rows with the SAME involution pi, so fragment keys come out in
// natural order. Mask uses key = kb + pi(slot). Max-free softmax as attn8.
__global__ __launch_bounds__(256) void attn13(const u16* __restrict__ qh,
                                              const u16* __restrict__ kh,
                                              const u16* __restrict__ vt,
                                              const float* __restrict__ qg,
                                              u16* __restrict__ y, int S) {
  const int bh = blockIdx.x & 31;
  const int g = blockIdx.x >> 5;
  const int d = g & 7, u = g >> 3;
  const int qb = (u == 0) ? 31 - d : (u == 1) ? 16 + d : (u == 2) ? 15 - d : d;
  const int h = bh & 15, b = bh >> 4;
  const int kvh = h >> 2;
  const int tid = threadIdx.x;
  const int wave = tid >> 6;
  const int lane = tid & 63;
  const int lg = lane >> 4, li = lane & 15;
  const int q0 = qb * 64 + wave * 16;
  const int qrow = q0 + li;
  const float mrow = 11.541560327111707f * fabsf(qg[h]);

  const u16* qp = qh + ((size_t)(b * 16 + h) * S + q0) * 64;
  const u16* kp = kh + (size_t)(b * 4 + kvh) * S * 64;
  const u16* vp = vt + (size_t)(b * 4 + kvh) * 64 * S;

  __shared__ __align__(16) u16 Ks[2][64][64];
  __shared__ __align__(16) u16 Vs[2][64][64];

  const int s_r0 = tid >> 3;              // 0..31
  // pi(row): swap bits 3,4 (blocks 8-15 <-> 16-23 within each 32)
  const int s_rp = (s_r0 & ~24) | ((s_r0 & 8) << 1) | ((s_r0 & 16) >> 1);
  const int s_c = (tid & 7) ^ ((tid >> 3) & 7);
  const int rdsw = li & 7;
  const f32x4 minit = {-mrow, -mrow, -mrow, -mrow};
  const f32x4 fz = {0.f, 0.f, 0.f, 0.f};
  const u16x8 ones_u = {0x3F80, 0x3F80, 0x3F80, 0x3F80,
                        0x3F80, 0x3F80, 0x3F80, 0x3F80};
  const bf16x8 onesb = *(const bf16x8*)&ones_u;

  // K rows staged with pi; V unchanged.
#define STAGE(buf, kb)                                                        \
  {                                                                           \
    const u16* gk = kp + (size_t)((kb) + s_rp) * 64 + s_c * 8;                \
    gl2lds16(gk, &Ks[buf][0][0] + (size_t)tid * 8);                           \
    gl2lds16(gk + (size_t)32 * 64, &Ks[buf][32][0] + (size_t)tid * 8);        \
    const u16* gv = vp + (size_t)s_r0 * S + (kb) + s_c * 8;                   \
    gl2lds16(gv, &Vs[buf][0][0] + (size_t)tid * 8);                           \
    gl2lds16(gv + (size_t)32 * S, &Vs[buf][32][0] + (size_t)tid * 8);         \
  }

  STAGE(0, 0)
  const bf16x8 qf0 = *(const bf16x8*)&qp[li * 64 + lg * 8];
  const bf16x8 qf1 = *(const bf16x8*)&qp[li * 64 + 32 + lg * 8];

  f32x4 o[4];
#pragma unroll
  for (int j = 0; j < 4; j++) o[j] = fz;
  f32x4 lsum = fz;

  int buf = 0;
  for (int tt = 0; tt <= qb; ++tt) {
    if (tt < qb) {
      STAGE(buf ^ 1, (tt + 1) * 64)
      asm volatile("s_waitcnt vmcnt(4)" ::: "memory");
    } else {
      asm volatile("s_waitcnt vmcnt(0)" ::: "memory");
    }
    __builtin_amdgcn_s_barrier();
    const int kb = tt * 64;
    f32x4 s[4];
    __builtin_amdgcn_s_setprio(1);
#pragma unroll
    for (int t = 0; t < 4; t++) {
      const bf16x8 ka =
          *(const bf16x8*)&Ks[buf][t * 16 + li][((lg) ^ rdsw) * 8];
      const bf16x8 kc =
          *(const bf16x8*)&Ks[buf][t * 16 + li][((lg + 4) ^ rdsw) * 8];
      s[t] = mfma16(ka, qf0, minit);
      s[t] = mfma16(kc, qf1, s[t]);
    }
    __builtin_amdgcn_s_setprio(0);
    float pv[16];
    if (tt < qb) {
#pragma unroll
      for (int t = 0; t < 4; t++)
#pragma unroll
        for (int r = 0; r < 4; r++) pv[t * 4 + r] = exp2f(s[t][r]);
    } else {
      // slot sigma = t*16+lg*4+r holds actual key kb + pi(sigma):
      // pi(sigma) = (t>>1)*32 + ((lg>>1)&1)*16 + (t&1)*8 + (lg&1)*4 + r
#pragma unroll
      for (int t = 0; t < 4; t++)
#pragma unroll
        for (int r = 0; r < 4; r++) {
          const int key = kb + ((t >> 1) << 5) + ((lg & 2) << 3) +
                          ((t & 1) << 3) + ((lg & 1) << 2) + r;
          pv[t * 4 + r] = exp2f(key > qrow ? -1e30f : s[t][r]);
        }
    }
    // pack adjacent-slot bf16 pairs
    unsigned w0 = cvtpk(pv[0], pv[1]),   w1 = cvtpk(pv[2], pv[3]);
    unsigned w2 = cvtpk(pv[4], pv[5]),   w3 = cvtpk(pv[6], pv[7]);
    unsigned w4 = cvtpk(pv[8], pv[9]),   w5 = cvtpk(pv[10], pv[11]);
    unsigned w6 = cvtpk(pv[12], pv[13]), w7 = cvtpk(pv[14], pv[15]);
    // permlane16_swap: vdst rows1,3 (lanes16-31,48-63) <-> vsrc rows0,2.
    // After swap, (w0,w1,w2,w3) IS the B-frag for keys 0..31 under pi,
    // and K-staging's pi makes the net key order natural.
    asm("v_permlane16_swap_b32 %0, %1" : "+v"(w0), "+v"(w2));
    asm("v_permlane16_swap_b32 %0, %1" : "+v"(w1), "+v"(w3));
    asm("v_permlane16_swap_b32 %0, %1" : "+v"(w4), "+v"(w6));
    asm("v_permlane16_swap_b32 %0, %1" : "+v"(w5), "+v"(w7));
    uint4 pb0u = {w0, w1, w2, w3};   // keys 0..31
    uint4 pb1u = {w4, w5, w6, w7};   // keys 32..63
    const bf16x8 pb0 = *(const bf16x8*)&pb0u;
    const bf16x8 pb1 = *(const bf16x8*)&pb1u;
    // PV: O^T = V^T * P^T; V^T frags from Vs (A-operand), keys natural order
    __builtin_amdgcn_s_setprio(1);
#pragma unroll
    for (int j = 0; j < 4; j++) {
      const bf16x8 v0 =
          *(const bf16x8*)&Vs[buf][j * 16 + li][((lg) ^ rdsw) * 8];
      const bf16x8 v1 =
          *(const bf16x8*)&Vs[buf][j * 16 + li][((lg + 4) ^ rdsw) * 8];
      o[j] = mfma16(v0, pb0, o[j]);
      o[j] = mfma16(v1, pb1, o[j]);
    }
    lsum = mfma16(onesb, pb0, lsum);
    lsum = mfma16(onesb, pb1, lsum);
    __builtin_amdgcn_s_setprio(0);
    __builtin_amdgcn_s_barrier();
    buf ^= 1;
  }
#undef STAGE
  // epilogue: lane holds q = q0+li; d = j*16 + lg*4 + r
  const float linv = 1.0f / lsum[0];
  u16* yp = &y[((size_t)(b * S + q0 + li)) * 1024 + h * 64];
#pragma unroll
  for (int j = 0; j < 4; j++) {
    uint2 wo;
    wo.x = cvtpk(o[j][0] * linv, o[j][1] * linv);
    wo.y = cvtpk(o[j][2] * linv, o[j][3] * linv);
    *(uint2*)(yp + j * 16 + lg * 4) = wo;
  }
}

extern "C" void kernel_launch(void* const* d_in, const int* in_sizes, int n_in,
                              void* d_out, int out_size, void* d_ws, size_t ws_size,
                              hipStream_t stream) {
  const float* x  = (const float*)d_in[0];
  const float* Wq = (const float*)d_in[1];
  const float* Wk = (const float*)d_in[2];
  const float* Wv = (const float*)d_in[3];
  const float* Wp = (const float*)d_in[4];
  const float* qg = (const float*)d_in[5];
  float* out = (float*)d_out;

  const int S = 2048;
  char* ws = (char*)d_ws;
  u16*    xb    = (u16*)(ws + 0);          // 8 MB
  u16*    wallb = (u16*)(ws + 8388608);    // 3 MB
  u16*    wpb   = (u16*)(ws + 11534336);   // 2 MB
  float2* tbl   = (float2*)(ws + 13631488);// 512 KB
  u16*    qf    = (u16*)(ws + 14155776);   // [4096][1536] bf16 (12 MB)
  u16*    qhb   = (u16*)(ws + 26738688);   // 8 MB
  u16*    khb   = (u16*)(ws + 35127296);   // 2 MB
  u16*    vtb   = (u16*)(ws + 37224448);   // 2 MB
  u16*    yb    = (u16*)(ws + 39321600);   // 8 MB -> 47710208
  if (ws_size < 47710208) return;

  megacast<<<3584, 256, 0, stream>>>(x, Wq, Wk, Wv, Wp, xb, wallb, wpb, tbl);

  // fused QKV projection: 128x64 tile -> 768 blocks = exactly 3/CU
  gemm_bt<128, 64, true><<<dim3(24, 32), 256, 0, stream>>>(xb, wallb, qf,
                                                           4096, 1536, 1024);

  // RMSNorm+RoPE (20 heads) + V transpose in one dispatch
  posttrans<<<20544, 256, 0, stream>>>(qf, qg, qhb, khb, vtb, S, tbl);

  attn13<<<1024, 256, 0, stream>>>(qhb, khb, vtb, qg, yb, S);

  // output projection: 64x128 tile -> 512 blocks = 2/CU
  gemm_bt<64, 128, false><<<dim3(8, 64), 256, 0, stream>>>(yb, wpb, out,
                                                           4096, 1024, 1024);
}

// Round 16
// 90.177 us; speedup vs baseline: 1.3070x; 1.2486x over previous
//
#include <hip/hip_runtime.h>

typedef unsigned short u16;
typedef __bf16 bf16_t;
typedef bf16_t bf16x8 __attribute__((ext_vector_type(8)));
typedef float f32x4 __attribute__((ext_vector_type(4)));
typedef u16 u16x8 __attribute__((ext_vector_type(8)));

__device__ __forceinline__ u16 f2bf(float f) {
  unsigned u = __float_as_uint(f);
  u += 0x7fffu + ((u >> 16) & 1u);
  return (u16)(u >> 16);
}

__device__ __forceinline__ unsigned cvtpk(float lo, float hi) {
  unsigned r;
  asm("v_cvt_pk_bf16_f32 %0, %1, %2" : "=v"(r) : "v"(lo), "v"(hi));
  return r;
}

__device__ __forceinline__ f32x4 mfma16(bf16x8 a, bf16x8 b, f32x4 c) {
  return __builtin_amdgcn_mfma_f32_16x16x32_bf16(a, b, c, 0, 0, 0);
}

__device__ __forceinline__ void gl2lds16(const u16* g, u16* l) {
  __builtin_amdgcn_global_load_lds(
      (__attribute__((address_space(1))) void*)(u16*)g,
      (__attribute__((address_space(3))) void*)l, 16, 0, 0);
}

__device__ __forceinline__ void cast8(const float* __restrict__ in,
                                      u16* __restrict__ out, int i) {
  float4 a = *(const float4*)&in[i];
  float4 b = *(const float4*)&in[i + 4];
  uint4 o;
  o.x = cvtpk(a.x, a.y);
  o.y = cvtpk(a.z, a.w);
  o.z = cvtpk(b.x, b.y);
  o.w = cvtpk(b.z, b.w);
  *(uint4*)&out[i] = o;
}

// ---------------- megacast: all f32->bf16 casts + trig table ----------------
__global__ __launch_bounds__(256) void megacast(
    const float* __restrict__ x, const float* __restrict__ Wq,
    const float* __restrict__ Wk, const float* __restrict__ Wv,
    const float* __restrict__ Wp, u16* __restrict__ xb,
    u16* __restrict__ wallb, u16* __restrict__ wpb,
    float2* __restrict__ tbl) {
  const int blk = blockIdx.x;
  const int tid = threadIdx.x;
  if (blk < 2048) {
    cast8(x, xb, (blk * 256 + tid) * 8);
  } else if (blk < 2560) {
    cast8(Wq, wallb, ((blk - 2048) * 256 + tid) * 8);
  } else if (blk < 2688) {
    cast8(Wk, wallb + 1048576, ((blk - 2560) * 256 + tid) * 8);
  } else if (blk < 2816) {
    cast8(Wv, wallb + 1310720, ((blk - 2688) * 256 + tid) * 8);
  } else if (blk < 3328) {
    cast8(Wp, wpb, ((blk - 2816) * 256 + tid) * 8);
  } else {
    const int idx = (blk - 3328) * 256 + tid;  // < 65536
    const int s = idx >> 5, i = idx & 31;
    float inv = exp2f(-(float)i * (13.287712379549449f / 32.0f));
    float fr = (float)s * inv;
    float sn, cs;
    sincosf(fr, &sn, &cs);
    tbl[idx] = make_float2(cs, sn);
  }
}

// ---------------- proj GEMM: 1D grid + XCD-chunked swizzle ------------------
template <int BM, int BN, int NTN, bool O16>
__global__ __launch_bounds__(256) void gemm_bt(const u16* __restrict__ A,
                                               const u16* __restrict__ B,
                                               void* __restrict__ Cv,
                                               int M, int N, int K) {
  constexpr int FM = BM / 32;
  constexpr int FN = BN / 32;
  constexpr int NL = (BM + BN) / 32;
  __shared__ __align__(16) u16 As[2][BM][64];
  __shared__ __align__(16) u16 Bs[2][BN][64];
  const int tid = threadIdx.x;
  const int lane = tid & 63;
  const int lg = lane >> 4, li = lane & 15;
  const int wave = tid >> 6;
  const int wr = (wave >> 1) * (BM / 2), wc = (wave & 1) * (BN / 2);
  // XCD-chunked: XCD (bid%8) owns a contiguous wid range -> A panels L2-hot
  const int wid = (blockIdx.x & 7) * (gridDim.x >> 3) + (blockIdx.x >> 3);
  const int m0 = (wid / NTN) * BM, n0 = (wid % NTN) * BN;

  const int s_r = tid >> 3;
  const int s_c = (tid & 7) ^ ((tid >> 3) & 7);
  const int rdsw = li & 7;

  auto GSTAGE = [&](int buf, int k0) {
    const u16* ga = &A[(size_t)(m0 + s_r) * K + k0 + s_c * 8];
#pragma unroll
    for (int i = 0; i < BM / 32; i++)
      gl2lds16(ga + (size_t)(i * 32) * K, &As[buf][i * 32][0] + (size_t)tid * 8);
    const u16* gb = &B[(size_t)(n0 + s_r) * K + k0 + s_c * 8];
#pragma unroll
    for (int i = 0; i < BN / 32; i++)
      gl2lds16(gb + (size_t)(i * 32) * K, &Bs[buf][i * 32][0] + (size_t)tid * 8);
  };

  const f32x4 fz = {0.f, 0.f, 0.f, 0.f};
  f32x4 acc[FM][FN];
#pragma unroll
  for (int i = 0; i < FM; i++)
#pragma unroll
    for (int j = 0; j < FN; j++) acc[i][j] = fz;

  GSTAGE(0, 0);
  int buf = 0;
  const int nk = K >> 6;
  for (int t = 0; t < nk; ++t) {
    if (t + 1 < nk) {
      GSTAGE(buf ^ 1, (t + 1) * 64);
      if constexpr (NL == 6)
        asm volatile("s_waitcnt vmcnt(6)" ::: "memory");
      else
        asm volatile("s_waitcnt vmcnt(8)" ::: "memory");
    } else {
      asm volatile("s_waitcnt vmcnt(0)" ::: "memory");
    }
    __builtin_amdgcn_s_barrier();
#pragma unroll
    for (int kk = 0; kk < 2; kk++) {
      bf16x8 af[FM], bfr[FN];
#pragma unroll
      for (int i = 0; i < FM; i++)
        af[i] = *(const bf16x8*)&As[buf][wr + i * 16 + li]
                                   [((kk * 4 + lg) ^ rdsw) * 8];
#pragma unroll
      for (int j = 0; j < FN; j++)
        bfr[j] = *(const bf16x8*)&Bs[buf][wc + j * 16 + li]
                                    [((kk * 4 + lg) ^ rdsw) * 8];
      __builtin_amdgcn_s_setprio(1);
#pragma unroll
      for (int i = 0; i < FM; i++)
#pragma unroll
        for (int j = 0; j < FN; j++) acc[i][j] = mfma16(af[i], bfr[j], acc[i][j]);
      __builtin_amdgcn_s_setprio(0);
    }
    __builtin_amdgcn_s_barrier();
    buf ^= 1;
  }
#pragma unroll
  for (int i = 0; i < FM; i++)
#pragma unroll
    for (int j = 0; j < FN; j++)
#pragma unroll
      for (int r = 0; r < 4; r++) {
        const size_t idx =
            (size_t)(m0 + wr + i * 16 + lg * 4 + r) * N + n0 + wc + j * 16 + li;
        if constexpr (O16)
          ((u16*)Cv)[idx] = f2bf(acc[i][j][r]);
        else
          ((float*)Cv)[idx] = acc[i][j][r];
      }
}

// ---------------- QKV GEMM with fused RMSNorm/RoPE/V-transpose epilogue -----
// BM=128, BN=64: each block's n-tile is exactly one head.
// ntile<16: q head (rms+rope+gain+0.125*log2e) -> qhb
// 16..19:   k head (rms+rope)                  -> khb
// 20..23:   v head (bf16 + transpose)          -> vtb
__global__ __launch_bounds__(256) void gemm_qkv(const u16* __restrict__ A,
                                                const u16* __restrict__ B,
                                                const float* __restrict__ qg,
                                                u16* __restrict__ qhb,
                                                u16* __restrict__ khb,
                                                u16* __restrict__ vtb,
                                                const float2* __restrict__ tbl) {
  const int K = 1024, S = 2048;
  __shared__ __align__(16) u16 As[2][128][64];   // 32 KB
  __shared__ __align__(16) u16 Bs[2][64][64];    // 16 KB
  const int tid = threadIdx.x;
  const int lane = tid & 63;
  const int lg = lane >> 4, li = lane & 15;
  const int wave = tid >> 6;
  const int wr = (wave >> 1) * 64, wc = (wave & 1) * 32;
  // XCD-chunked swizzle: grid 768, XCD x gets wids [x*96, x*96+96) = 4 m-tiles
  const int wid = (blockIdx.x & 7) * 96 + (blockIdx.x >> 3);
  const int mt = wid / 24;
  const int ntile = wid - mt * 24;
  const int m0 = mt * 128;

  const int s_r = tid >> 3;
  const int s_c = (tid & 7) ^ ((tid >> 3) & 7);
  const int rdsw = li & 7;

  auto GSTAGE = [&](int buf, int k0) {
    const u16* ga = &A[(size_t)(m0 + s_r) * K + k0 + s_c * 8];
#pragma unroll
    for (int i = 0; i < 4; i++)
      gl2lds16(ga + (size_t)(i * 32) * K, &As[buf][i * 32][0] + (size_t)tid * 8);
    const u16* gb = &B[(size_t)(ntile * 64 + s_r) * K + k0 + s_c * 8];
#pragma unroll
    for (int i = 0; i < 2; i++)
      gl2lds16(gb + (size_t)(i * 32) * K, &Bs[buf][i * 32][0] + (size_t)tid * 8);
  };

  const f32x4 fz = {0.f, 0.f, 0.f, 0.f};
  f32x4 acc[4][2];
#pragma unroll
  for (int i = 0; i < 4; i++)
#pragma unroll
    for (int j = 0; j < 2; j++) acc[i][j] = fz;

  GSTAGE(0, 0);
  int buf = 0;
  for (int t = 0; t < 16; ++t) {
    if (t + 1 < 16) {
      GSTAGE(buf ^ 1, (t + 1) * 64);
      asm volatile("s_waitcnt vmcnt(6)" ::: "memory");
    } else {
      asm volatile("s_waitcnt vmcnt(0)" ::: "memory");
    }
    __builtin_amdgcn_s_barrier();
#pragma unroll
    for (int kk = 0; kk < 2; kk++) {
      bf16x8 af[4], bfr[2];
#pragma unroll
      for (int i = 0; i < 4; i++)
        af[i] = *(const bf16x8*)&As[buf][wr + i * 16 + li]
                                   [((kk * 4 + lg) ^ rdsw) * 8];
#pragma unroll
      for (int j = 0; j < 2; j++)
        bfr[j] = *(const bf16x8*)&Bs[buf][wc + j * 16 + li]
                                    [((kk * 4 + lg) ^ rdsw) * 8];
      __builtin_amdgcn_s_setprio(1);
#pragma unroll
      for (int i = 0; i < 4; i++)
#pragma unroll
        for (int j = 0; j < 2; j++) acc[i][j] = mfma16(af[i], bfr[j], acc[i][j]);
      __builtin_amdgcn_s_setprio(0);
    }
    __builtin_amdgcn_s_barrier();
    buf ^= 1;
  }

  // ---- fused epilogue (all waves past final barrier; LDS reusable) ----
  if (ntile < 20) {
    // q/k: RMSNorm over 64 cols (this wave has 32; partner wave has the rest)
    float* acc_t = (float*)&As[0][0][0];  // [4][64][32] f32 = 32 KB
    float* sw = (float*)&Bs[0][0][0];     // [4][64] f32 = 1 KB
    float ssq[4][4];
#pragma unroll
    for (int i = 0; i < 4; i++)
#pragma unroll
      for (int r = 0; r < 4; r++) {
        float s2 = acc[i][0][r] * acc[i][0][r] + acc[i][1][r] * acc[i][1][r];
        s2 += __shfl_xor(s2, 1);
        s2 += __shfl_xor(s2, 2);
        s2 += __shfl_xor(s2, 4);
        s2 += __shfl_xor(s2, 8);
        ssq[i][r] = s2;
        const int rowidx = i * 16 + lg * 4 + r;
        if (li == 0) sw[wave * 64 + rowidx] = s2;
#pragma unroll
        for (int j = 0; j < 2; j++)
          acc_t[wave * 2048 + rowidx * 32 + j * 16 + li] = acc[i][j][r];
      }
    __syncthreads();
    const int pw = wave ^ 1;
    const float qsc =
        (ntile < 16) ? 0.18033688011112042f * qg[ntile] : 1.0f;
#pragma unroll
    for (int i = 0; i < 4; i++)
#pragma unroll
      for (int r = 0; r < 4; r++) {
        const int rowidx = i * 16 + lg * 4 + r;
        const float stot = ssq[i][r] + sw[pw * 64 + rowidx];
        const float rn = rsqrtf(stot * (1.0f / 64.0f) + 1.1920929e-07f);
        const int grow = m0 + wr + rowidx;
        const int srow = grow & 2047;
        const int bb = grow >> 11;
#pragma unroll
        for (int j = 0; j < 2; j++) {
          const int fi = j * 16 + li;
          const float2 cs2 = tbl[srow * 32 + fi];
          const float vn = acc[i][j][r] * rn;
          const float pvn = acc_t[pw * 2048 + rowidx * 32 + fi] * rn;
          float o = (wc == 0) ? (vn * cs2.x + pvn * cs2.y)
                              : (vn * cs2.x - pvn * cs2.y);
          o *= qsc;
          const int col = wc + fi;
          if (ntile < 16)
            qhb[((size_t)(bb * 16 + ntile) * S + srow) * 64 + col] = f2bf(o);
          else
            khb[((size_t)(bb * 4 + (ntile - 16)) * S + srow) * 64 + col] =
                f2bf(o);
        }
      }
  } else {
    // v: bf16 + transpose via LDS -> vtb[(b*4+kv)*64 + d][s]
    u16* T = (u16*)&As[0][0][0];  // [128][67] u16 = 16.75 KB
#pragma unroll
    for (int i = 0; i < 4; i++)
#pragma unroll
      for (int j = 0; j < 2; j++)
#pragma unroll
        for (int r = 0; r < 4; r++)
          T[(wr + i * 16 + lg * 4 + r) * 67 + wc + j * 16 + li] =
              f2bf(acc[i][j][r]);
    __syncthreads();
    const int kv = ntile - 20;
    const int d = tid >> 2;
    const int sq = (tid & 3) * 32;
    const int bb = m0 >> 11;
    const int s0 = (m0 & 2047) + sq;
    unsigned* dst = (unsigned*)(vtb + ((size_t)(bb * 4 + kv) * 64 + d) * S + s0);
#pragma unroll
    for (int k2 = 0; k2 < 16; k2++) {
      unsigned lo = T[(sq + 2 * k2) * 67 + d];
      unsigned hi = T[(sq + 2 * k2 + 1) * 67 + d];
      dst[k2] = lo | (hi << 16);
    }
  }
}

// ---------------- flash attention v13 (in-register P, verified) -------------
__global__ __launch_bounds__(256) void attn13(const u16* __restrict__ qh,
                                              const u16* __restrict__ kh,
                                              const u16* __restrict__ vt,
                                              const float* __restrict__ qg,
                                              u16* __restrict__ y, int S) {
  const int bh = blockIdx.x & 31;
  const int g = blockIdx.x >> 5;
  const int d = g & 7, u = g >> 3;
  const int qb = (u == 0) ? 31 - d : (u == 1) ? 16 + d : (u == 2) ? 15 - d : d;
  const int h = bh & 15, b = bh >> 4;
  const int kvh = h >> 2;
  const int tid = threadIdx.x;
  const int wave = tid >> 6;
  const int lane = tid & 63;
  const int lg = lane >> 4, li = lane & 15;
  const int q0 = qb * 64 + wave * 16;
  const int qrow = q0 + li;
  const float mrow = 11.541560327111707f * fabsf(qg[h]);

  const u16* qp = qh + ((size_t)(b * 16 + h) * S + q0) * 64;
  const u16* kp = kh + (size_t)(b * 4 + kvh) * S * 64;
  const u16* vp = vt + (size_t)(b * 4 + kvh) * 64 * S;

  __shared__ __align__(16) u16 Ks[2][64][64];
  __shared__ __align__(16) u16 Vs[2][64][64];

  const int s_r0 = tid >> 3;
  const int s_rp = (s_r0 & ~24) | ((s_r0 & 8) << 1) | ((s_r0 & 16) >> 1);
  const int s_c = (tid & 7) ^ ((tid >> 3) & 7);
  const int rdsw = li & 7;
  const f32x4 minit = {-mrow, -mrow, -mrow, -mrow};
  const f32x4 fz = {0.f, 0.f, 0.f, 0.f};
  const u16x8 ones_u = {0x3F80, 0x3F80, 0x3F80, 0x3F80,
                        0x3F80, 0x3F80, 0x3F80, 0x3F80};
  const bf16x8 onesb = *(const bf16x8*)&ones_u;

#define STAGE(buf, kb)                                                        \
  {                                                                           \
    const u16* gk = kp + (size_t)((kb) + s_rp) * 64 + s_c * 8;                \
    gl2lds16(gk, &Ks[buf][0][0] + (size_t)tid * 8);                           \
    gl2lds16(gk + (size_t)32 * 64, &Ks[buf][32][0] + (size_t)tid * 8);        \
    const u16* gv = vp + (size_t)s_r0 * S + (kb) + s_c * 8;                   \
    gl2lds16(gv, &Vs[buf][0][0] + (size_t)tid * 8);                           \
    gl2lds16(gv + (size_t)32 * S, &Vs[buf][32][0] + (size_t)tid * 8);         \
  }

  STAGE(0, 0)
  const bf16x8 qf0 = *(const bf16x8*)&qp[li * 64 + lg * 8];
  const bf16x8 qf1 = *(const bf16x8*)&qp[li * 64 + 32 + lg * 8];

  f32x4 o[4];
#pragma unroll
  for (int j = 0; j < 4; j++) o[j] = fz;
  f32x4 lsum = fz;

  int buf = 0;
  for (int tt = 0; tt <= qb; ++tt) {
    if (tt < qb) {
      STAGE(buf ^ 1, (tt + 1) * 64)
      asm volatile("s_waitcnt vmcnt(4)" ::: "memory");
    } else {
      asm volatile("s_waitcnt vmcnt(0)" ::: "memory");
    }
    __builtin_amdgcn_s_barrier();
    const int kb = tt * 64;
    f32x4 s[4];
    __builtin_amdgcn_s_setprio(1);
#pragma unroll
    for (int t = 0; t < 4; t++) {
      const bf16x8 ka =
          *(const bf16x8*)&Ks[buf][t * 16 + li][((lg) ^ rdsw) * 8];
      const bf16x8 kc =
          *(const bf16x8*)&Ks[buf][t * 16 + li][((lg + 4) ^ rdsw) * 8];
      s[t] = mfma16(ka, qf0, minit);
      s[t] = mfma16(kc, qf1, s[t]);
    }
    __builtin_amdgcn_s_setprio(0);
    float pv[16];
    if (tt < qb) {
#pragma unroll
      for (int t = 0; t < 4; t++)
#pragma unroll
        for (int r = 0; r < 4; r++) pv[t * 4 + r] = exp2f(s[t][r]);
    } else {
#pragma unroll
      for (int t = 0; t < 4; t++)
#pragma unroll
        for (int r = 0; r < 4; r++) {
          const int key = kb + ((t >> 1) << 5) + ((lg & 2) << 3) +
                          ((t & 1) << 3) + ((lg & 1) << 2) + r;
          pv[t * 4 + r] = exp2f(key > qrow ? -1e30f : s[t][r]);
        }
    }
    unsigned w0 = cvtpk(pv[0], pv[1]),   w1 = cvtpk(pv[2], pv[3]);
    unsigned w2 = cvtpk(pv[4], pv[5]),   w3 = cvtpk(pv[6], pv[7]);
    unsigned w4 = cvtpk(pv[8], pv[9]),   w5 = cvtpk(pv[10], pv[11]);
    unsigned w6 = cvtpk(pv[12], pv[13]), w7 = cvtpk(pv[14], pv[15]);
    asm("v_permlane16_swap_b32 %0, %1" : "+v"(w0), "+v"(w2));
    asm("v_permlane16_swap_b32 %0, %1" : "+v"(w1), "+v"(w3));
    asm("v_permlane16_swap_b32 %0, %1" : "+v"(w4), "+v"(w6));
    asm("v_permlane16_swap_b32 %0, %1" : "+v"(w5), "+v"(w7));
    uint4 pb0u = {w0, w1, w2, w3};
    uint4 pb1u = {w4, w5, w6, w7};
    const bf16x8 pb0 = *(const bf16x8*)&pb0u;
    const bf16x8 pb1 = *(const bf16x8*)&pb1u;
    __builtin_amdgcn_s_setprio(1);
#pragma unroll
    for (int j = 0; j < 4; j++) {
      const bf16x8 v0 =
          *(const bf16x8*)&Vs[buf][j * 16 + li][((lg) ^ rdsw) * 8];
      const bf16x8 v1 =
          *(const bf16x8*)&Vs[buf][j * 16 + li][((lg + 4) ^ rdsw) * 8];
      o[j] = mfma16(v0, pb0, o[j]);
      o[j] = mfma16(v1, pb1, o[j]);
    }
    lsum = mfma16(onesb, pb0, lsum);
    lsum = mfma16(onesb, pb1, lsum);
    __builtin_amdgcn_s_setprio(0);
    __builtin_amdgcn_s_barrier();
    buf ^= 1;
  }
#undef STAGE
  const float linv = 1.0f / lsum[0];
  u16* yp = &y[((size_t)(b * S + q0 + li)) * 1024 + h * 64];
#pragma unroll
  for (int j = 0; j < 4; j++) {
    uint2 wo;
    wo.x = cvtpk(o[j][0] * linv, o[j][1] * linv);
    wo.y = cvtpk(o[j][2] * linv, o[j][3] * linv);
    *(uint2*)(yp + j * 16 + lg * 4) = wo;
  }
}

extern "C" void kernel_launch(void* const* d_in, const int* in_sizes, int n_in,
                              void* d_out, int out_size, void* d_ws, size_t ws_size,
                              hipStream_t stream) {
  const float* x  = (const float*)d_in[0];
  const float* Wq = (const float*)d_in[1];
  const float* Wk = (const float*)d_in[2];
  const float* Wv = (const float*)d_in[3];
  const float* Wp = (const float*)d_in[4];
  const float* qg = (const float*)d_in[5];
  float* out = (float*)d_out;

  const int S = 2048;
  char* ws = (char*)d_ws;
  u16*    xb    = (u16*)(ws + 0);          // 8 MB
  u16*    wallb = (u16*)(ws + 8388608);    // 3 MB
  u16*    wpb   = (u16*)(ws + 11534336);   // 2 MB
  float2* tbl   = (float2*)(ws + 13631488);// 512 KB
  u16*    qhb   = (u16*)(ws + 14155776);   // 8 MB
  u16*    khb   = (u16*)(ws + 22544384);   // 2 MB
  u16*    vtb   = (u16*)(ws + 24641536);   // 2 MB
  u16*    yb    = (u16*)(ws + 26738688);   // 8 MB -> 35127296
  if (ws_size < 35127296) return;

  megacast<<<3584, 256, 0, stream>>>(x, Wq, Wk, Wv, Wp, xb, wallb, wpb, tbl);

  // fused QKV projection + RMSNorm/RoPE/V-transpose: 768 blocks = 3/CU
  gemm_qkv<<<768, 256, 0, stream>>>(xb, wallb, qg, qhb, khb, vtb, tbl);

  attn13<<<1024, 256, 0, stream>>>(qhb, khb, vtb, qg, yb, S);

  // output projection: 64x128 tile, 1D grid 512 = 2/CU, XCD-chunked
  gemm_bt<64, 128, 8, false><<<512, 256, 0, stream>>>(yb, wpb, out,
                                                      4096, 1024, 1024);
}